// Round 10
// baseline (637.884 us; speedup 1.0000x reference)
//
#include <hip/hip_runtime.h>
#include <hip/hip_bf16.h>

#define N_TOK 8192
#define C_DIM 1024
#define FF_DIM 4096
#define NE 4
#define ROWS_MAX 17408           // max padded packed rows (16384 + 4*256 slack)
#define TOTB256 68               // ROWS_MAX / 256
#define PLANE_E 17825792         // ROWS_MAX * C_DIM (elems per f32 partial plane)

typedef __attribute__((ext_vector_type(8))) short bf16x8;
typedef __attribute__((ext_vector_type(4))) float f32x4;

__device__ __forceinline__ unsigned short f2bf(float f) {
    union { float f; unsigned int u; } v; v.f = f;
    return (unsigned short)((v.u + 0x7FFFu + ((v.u >> 16) & 1u)) >> 16);
}
__device__ __forceinline__ float bf2f(unsigned short u) {
    union { unsigned int u; float f; } v; v.u = ((unsigned int)u) << 16;
    return v.f;
}

__device__ __forceinline__ void gload_lds16(const void* g, void* l) {
    __builtin_amdgcn_global_load_lds(
        (const __attribute__((address_space(1))) unsigned int*)g,
        (__attribute__((address_space(3))) unsigned int*)l, 16, 0, 0);
}

#define WAITV(N) do { asm volatile("s_waitcnt vmcnt(" #N ")" ::: "memory"); __builtin_amdgcn_sched_barrier(0); } while (0)
#define WAITL0()  do { asm volatile("s_waitcnt lgkmcnt(0)" ::: "memory"); __builtin_amdgcn_sched_barrier(0); } while (0)
#define BAR()     do { __builtin_amdgcn_s_barrier(); __builtin_amdgcn_sched_barrier(0); } while (0)
#define PRIO1()   __builtin_amdgcn_s_setprio(1)
#define PRIO0()   __builtin_amdgcn_s_setprio(0)

// bijective XCD-aware block swizzle (m204): contiguous id-chunks per XCD (k_down)
__device__ __forceinline__ int2 xcd_swz(int gx, int gy) {
    int wg = blockIdx.y * gx + blockIdx.x;
    int nwg = gx * gy;
    int q = nwg >> 3, r = nwg & 7;
    int xcd = wg & 7, idx = wg >> 3;
    int swz = (xcd < r) ? (xcd * (q + 1) + idx) : (r * (q + 1) + (xcd - r) * q + idx);
    return make_int2(swz % gx, swz / gx);
}

// gateup strip swizzle (gx==32 only): each XCD owns a 4-bx column strip; its 32
// concurrent blocks form 4bx x 8by -> B working set L2-resident.
__device__ __forceinline__ int2 strip_swz32() {
    int wg = blockIdx.y * 32 + blockIdx.x;
    int xcd = wg & 7, idx = wg >> 3;
    int bx = xcd * 4 + (idx & 3);
    int by = (idx >> 4) * 4 + ((idx >> 2) & 3);
    return make_int2(bx, by);
}

// ------- transpose+convert: src fp32 [z][R][S] -> dst bf16 [z][S][R]
__global__ void k_tconv(const float* __restrict__ src0, unsigned short* __restrict__ dst0,
                        int R, int S, size_t dz, int perm, int guoff) {
    __shared__ float tile[64][65];
    const float* src = src0 + (size_t)blockIdx.z * R * S;
    unsigned short* dst = dst0 + (size_t)blockIdx.z * dz;
    const int tc = blockIdx.x * 64;
    const int tr = blockIdx.y * 64;
    const int tid = threadIdx.x;
    const int lr = tid >> 4;          // 0..15
    const int lc4 = (tid & 15) * 4;   // 0..60
    #pragma unroll
    for (int i = 0; i < 64; i += 16) {
        float4 v = *(const float4*)(src + (size_t)(tr + lr + i) * S + tc + lc4);
        tile[lr + i][lc4 + 0] = v.x;
        tile[lr + i][lc4 + 1] = v.y;
        tile[lr + i][lc4 + 2] = v.z;
        tile[lr + i][lc4 + 3] = v.w;
    }
    __syncthreads();
    const int oc = tid >> 4;          // 0..15
    const int r4 = (tid & 15) * 4;    // 0..60
    #pragma unroll
    for (int i = 0; i < 64; i += 16) {
        int cp = tc + oc + i;
        int rowo = perm ? (32 * (cp >> 4) + (cp & 15) + guoff) : cp;
        ushort4 o;
        o.x = f2bf(tile[r4 + 0][oc + i]);
        o.y = f2bf(tile[r4 + 1][oc + i]);
        o.z = f2bf(tile[r4 + 2][oc + i]);
        o.w = f2bf(tile[r4 + 3][oc + i]);
        *(ushort4*)(dst + (size_t)rowo * R + tr + r4) = o;
    }
}

// ---------------- router: fp32 logits, softmax, top-2 -> cw[N][4]; also emits xb ----------------
__global__ void k_router(const float* __restrict__ x, const float* __restrict__ wr,
                         float* __restrict__ cw, unsigned short* __restrict__ xb) {
    int wv = threadIdx.x >> 6, lane = threadIdx.x & 63;
    int n = blockIdx.x * 4 + wv;
    const float* xr = x + (size_t)n * C_DIM;
    unsigned short* xbr = xb + (size_t)n * C_DIM;
    const float4* wr4 = (const float4*)wr;
    float p0 = 0.f, p1 = 0.f, p2 = 0.f, p3 = 0.f;
    for (int j = 0; j < C_DIM / 64; ++j) {
        int c = j * 64 + lane;
        float xv = xr[c];
        xbr[c] = f2bf(xv);
        float4 w = wr4[c];
        p0 += xv * w.x; p1 += xv * w.y; p2 += xv * w.z; p3 += xv * w.w;
    }
    #pragma unroll
    for (int off = 32; off > 0; off >>= 1) {
        p0 += __shfl_down(p0, off);
        p1 += __shfl_down(p1, off);
        p2 += __shfl_down(p2, off);
        p3 += __shfl_down(p3, off);
    }
    if (lane == 0) {
        float l[NE] = {p0, p1, p2, p3};
        float mx = fmaxf(fmaxf(l[0], l[1]), fmaxf(l[2], l[3]));
        float e0[NE]; float s = 0.f;
        #pragma unroll
        for (int i = 0; i < NE; ++i) { e0[i] = expf(l[i] - mx); s += e0[i]; }
        #pragma unroll
        for (int i = 0; i < NE; ++i) e0[i] /= s;
        int i1 = 0;
        #pragma unroll
        for (int i = 1; i < NE; ++i) if (e0[i] > e0[i1]) i1 = i;
        int i2 = -1;
        #pragma unroll
        for (int i = 0; i < NE; ++i) { if (i == i1) continue; if (i2 < 0 || e0[i] > e0[i2]) i2 = i; }
        float o[NE] = {0.f, 0.f, 0.f, 0.f};
        o[i1] = e0[i1]; o[i2] = e0[i2];
        *(float4*)(cw + (size_t)n * 4) = make_float4(o[0], o[1], o[2], o[3]);
    }
}

// ---------------- build per-expert token lists (deterministic, token-id order) ----------------
__global__ void k_build(const float* __restrict__ cw, int* __restrict__ rowlist,
                        float* __restrict__ cwg, int* __restrict__ pos2, int* __restrict__ meta) {
    __shared__ int lcnt[256][NE];
    int tid = threadIdx.x;
    int t0 = tid * 32;
    int c[NE] = {0, 0, 0, 0};
    for (int i = 0; i < 32; ++i) {
        const float* w = cw + (size_t)(t0 + i) * NE;
        #pragma unroll
        for (int e = 0; e < NE; ++e) if (w[e] > 0.f) c[e]++;
    }
    #pragma unroll
    for (int e = 0; e < NE; ++e) lcnt[tid][e] = c[e];
    __syncthreads();
    if (tid == 0) {
        int tot[NE] = {0, 0, 0, 0};
        for (int i = 0; i < 256; ++i)
            #pragma unroll
            for (int e = 0; e < NE; ++e) { int v = lcnt[i][e]; lcnt[i][e] = tot[e]; tot[e] += v; }
        int off = 0;
        #pragma unroll
        for (int e = 0; e < NE; ++e) {
            meta[e] = tot[e];
            int p = (tot[e] + 255) & ~255;
            meta[4 + e] = p;
            meta[8 + e] = off;
            off += p;
        }
        meta[12] = off;
    }
    __syncthreads();
    int pos[NE];
    #pragma unroll
    for (int e = 0; e < NE; ++e) pos[e] = lcnt[tid][e];
    for (int i = 0; i < 32; ++i) {
        int t = t0 + i;
        const float* w = cw + (size_t)t * NE;
        int sl = 0;
        #pragma unroll
        for (int e = 0; e < NE; ++e) if (w[e] > 0.f) {
            int p = meta[8 + e] + pos[e]++;
            rowlist[p] = t;
            cwg[p] = w[e];
            pos2[t * 2 + sl] = p;
            sl++;
        }
    }
    __syncthreads();
    if (tid < NE) {
        int e = tid;
        for (int p = meta[e]; p < meta[4 + e]; ++p) {
            rowlist[meta[8 + e] + p] = 0;
            cwg[meta[8 + e] + p] = 0.f;
        }
    }
}

// ================= 8-phase full-hoist 256x256 core (R8): shared macros =================
#define SLOT_E 8192   // elems per unit slot

#define STAGE_U(P0, P1, slot, kofs) do { \
    gload_lds16((P0) + (kofs), smem + (slot) * SLOT_E + dc0); \
    gload_lds16((P1) + (kofs), smem + (slot) * SLOT_E + dc1); } while (0)
#define STG_A(slot, kofs) STAGE_U(aptr0, aptr1, slot, kofs)
#define STG_B(slot, kofs) STAGE_U(bptr0, bptr1, slot, kofs)

#define LDAL(bk, s) do { _Pragma("unroll") \
    for (int m_ = 0; m_ < 4; ++m_) af[bk][m_] = *(const bf16x8*)&smem[(s) * SLOT_E + rdA + m_ * 512]; } while (0)
#define LDAH(bk, s) do { _Pragma("unroll") \
    for (int m_ = 0; m_ < 4; ++m_) af[bk][m_] = *(const bf16x8*)&smem[(s) * SLOT_E + rdA + (4 + m_) * 512]; } while (0)
#define LDB_(bk, s) do { _Pragma("unroll") \
    for (int n_ = 0; n_ < 4; ++n_) bv[bk][n_] = *(const bf16x8*)&smem[(s) * SLOT_E + rdB + n_ * 512]; } while (0)

#define MMLO(ab, bb) do { _Pragma("unroll") \
    for (int m_ = 0; m_ < 4; ++m_) \
        _Pragma("unroll") \
        for (int n_ = 0; n_ < 4; ++n_) \
            acc[m_][n_] = __builtin_amdgcn_mfma_f32_16x16x32_bf16(af[ab][m_], bv[bb][n_], acc[m_][n_], 0, 0, 0); } while (0)
#define MMHI(ab, bb) do { _Pragma("unroll") \
    for (int m_ = 0; m_ < 4; ++m_) \
        _Pragma("unroll") \
        for (int n_ = 0; n_ < 4; ++n_) \
            acc[4 + m_][n_] = __builtin_amdgcn_mfma_f32_16x16x32_bf16(af[ab][m_], bv[bb][n_], acc[4 + m_][n_], 0, 0, 0); } while (0)

#define ITER8H(kb) do { \
    /* ph0 */ STG_A(6, (kb) + 96);  BAR(); WAITL0();           PRIO1(); LDAH(1, 0);              MMLO(0, 0); PRIO0(); BAR(); \
    /* ph1 */ STG_B(7, (kb) + 96);  BAR(); WAITL0();           PRIO1(); LDAL(0, 2); LDB_(1, 3);  MMHI(1, 0); PRIO0(); BAR(); \
    /* ph2 */ STG_A(0, (kb) + 128); BAR(); WAITL0(); WAITV(6); PRIO1(); LDAH(1, 2);              MMLO(0, 1); PRIO0(); BAR(); \
    /* ph3 */ STG_B(1, (kb) + 128); BAR(); WAITL0();           PRIO1(); LDAL(0, 4); LDB_(0, 5);  MMHI(1, 1); PRIO0(); BAR(); \
    /* ph4 */ STG_A(2, (kb) + 160); BAR(); WAITL0(); WAITV(4); PRIO1(); LDAH(1, 4);              MMLO(0, 0); PRIO0(); BAR(); \
    /* ph5 */ STG_B(3, (kb) + 160); BAR(); WAITL0();           PRIO1(); LDAL(0, 6); LDB_(1, 7);  MMHI(1, 0); PRIO0(); BAR(); \
    /* ph6 */ STG_A(4, (kb) + 192); BAR(); WAITL0(); WAITV(6); PRIO1(); LDAH(1, 6);              MMLO(0, 1); PRIO0(); BAR(); \
    /* ph7 */ STG_B(5, (kb) + 192); BAR(); WAITL0(); WAITV(4); PRIO1(); LDAL(0, 0); LDB_(0, 1);  MMHI(1, 1); PRIO0(); BAR(); \
} while (0)

#define ITER8H_LAST(kb) do { \
    STG_A(6, (kb) + 96); BAR(); WAITL0();           PRIO1(); LDAH(1, 0);              MMLO(0, 0); PRIO0(); BAR(); \
    STG_B(7, (kb) + 96); BAR(); WAITL0();           PRIO1(); LDAL(0, 2); LDB_(1, 3);  MMHI(1, 0); PRIO0(); BAR(); \
                         BAR(); WAITL0(); WAITV(4); PRIO1(); LDAH(1, 2);              MMLO(0, 1); PRIO0(); BAR(); \
                         BAR(); WAITL0();           PRIO1(); LDAL(0, 4); LDB_(0, 5);  MMHI(1, 1); PRIO0(); BAR(); \
                         BAR(); WAITL0(); WAITV(0); PRIO1(); LDAH(1, 4);              MMLO(0, 0); PRIO0(); BAR(); \
                         BAR(); WAITL0();           PRIO1(); LDAL(0, 6); LDB_(1, 7);  MMHI(1, 0); PRIO0(); BAR(); \
                         BAR(); WAITL0();           PRIO1(); LDAH(1, 6);              MMLO(0, 1); PRIO0(); BAR(); \
                         BAR(); WAITL0();           PRIO1();                          MMHI(1, 1); PRIO0(); BAR(); \
} while (0)

// ---------------- merged gate+up GEMM (gathered A rows), silu epilogue ----------------
__global__ __launch_bounds__(512, 1) void k_gateup(
    const unsigned short* __restrict__ xb,
    const unsigned short* __restrict__ wgut,
    const int* __restrict__ rowlist,
    const int* __restrict__ meta,
    unsigned short* __restrict__ h,
    int cbase)
{
    extern __shared__ unsigned short smem[];
    int2 sb = strip_swz32();
    const int bx = sb.x, by = sb.y;
    const int p0 = cbase + by * 256;
    if (p0 >= meta[12]) return;
    const int e = (p0 >= meta[9]) + (p0 >= meta[10]) + (p0 >= meta[11]);

    const int tid = threadIdx.x;
    const int wid = tid >> 6, lane = tid & 63;
    const int wm = wid >> 2, wn = wid & 3;
    const int lrow = lane & 15, lkq = lane >> 4;

    const int lsub = lane >> 2;                        // 0..15
    const int kc = ((lane & 3) ^ ((lane >> 3) & 3)) * 8;
    const int row0 = 32 * wid + lsub;
    const int dc0 = wid * 1024, dc1 = dc0 + 512;       // linear dest

    const unsigned short* aptr0 = xb + (size_t)rowlist[p0 + row0] * C_DIM + kc;
    const unsigned short* aptr1 = xb + (size_t)rowlist[p0 + row0 + 16] * C_DIM + kc;
    const unsigned short* Bb = wgut + (size_t)e * (2 * C_DIM * FF_DIM) + (size_t)(bx * 256) * C_DIM;
    const unsigned short* bptr0 = Bb + (size_t)row0 * C_DIM + kc;
    const unsigned short* bptr1 = Bb + (size_t)(row0 + 16) * C_DIM + kc;

    const int q8 = (4 * lrow + (lkq ^ ((lrow >> 1) & 3))) * 8;
    const int rdA = wm * 4096 + q8;    // granule base wm*8 * 512
    const int rdB = wn * 2048 + q8;    // granule base wn*4 * 512

    f32x4 acc[8][4] = {};
    bf16x8 af[2][4], bv[2][4];

    STG_A(0, 0);
    STG_B(1, 0);
    STG_A(2, 32);
    STG_B(3, 32);
    STG_A(4, 64);
    STG_B(5, 64);
    WAITV(4);          // confirms slots 0..3; {4,5} in flight
    BAR();
    LDAL(0, 0);        // prologue pre-read for ph0
    LDB_(0, 1);

    const int NI = C_DIM / 128;            // 8
    #pragma unroll 1
    for (int i = 0; i < NI - 1; ++i) {
        const int kb = 128 * i;
        ITER8H(kb);
    }
    ITER8H_LAST(128 * (NI - 1));

    // epilogue: h = silu(gate) * up
    const int ffb = bx * 128 + wn * 32;
    #pragma unroll
    for (int mi = 0; mi < 8; ++mi) {
        int row = by * 256 + wm * 128 + mi * 16 + lkq * 4;   // chunk-relative h row
        #pragma unroll
        for (int j = 0; j < 2; ++j) {
            int ff = ffb + 16 * j + lrow;
            f32x4 g = acc[mi][2 * j];
            f32x4 u = acc[mi][2 * j + 1];
            #pragma unroll
            for (int r = 0; r < 4; ++r) {
                float gv = g[r];
                float hv = gv / (1.f + __expf(-gv)) * u[r];
                h[(size_t)(row + r) * FF_DIM + ff] = f2bf(hv);
            }
        }
    }
}

// ---------------- down GEMM, R8 core, K-sliced (z = K-slice when NSLICE=2) ----------------
// F32OUT=1: writes cwg-scaled f32 partials to plane blockIdx.z of yd32 (K-split
// path; fixes the 272-tile/2-round packing tail: 544 half-K blocks pack into
// ~2.1 thin rounds). F32OUT=0: legacy single-slice bf16 yd path (fallback when
// workspace lacks room for the 2 x 71 MB f32 planes).
template<int F32OUT>
__global__ __launch_bounds__(512, 1) void k_down(
    const unsigned short* __restrict__ h,
    const unsigned short* __restrict__ wdt,
    const float* __restrict__ cwg,
    const int* __restrict__ meta,
    unsigned short* __restrict__ yd,
    float* __restrict__ yd32,
    int cbase, int ni)
{
    extern __shared__ unsigned short smem[];
    int2 sb = xcd_swz(gridDim.x, gridDim.y);
    const int bx = sb.x, by = sb.y;
    const int p0 = cbase + by * 256;
    if (p0 >= meta[12]) return;
    const int e = (p0 >= meta[9]) + (p0 >= meta[10]) + (p0 >= meta[11]);
    const int kz = blockIdx.z;
    const int kbase = kz * (ni * 128);

    const int tid = threadIdx.x;
    const int wid = tid >> 6, lane = tid & 63;
    const int wm = wid >> 2, wn = wid & 3;
    const int lrow = lane & 15, lkq = lane >> 4;

    const int lsub = lane >> 2;
    const int kc = ((lane & 3) ^ ((lane >> 3) & 3)) * 8;
    const int row0 = 32 * wid + lsub;
    const int dc0 = wid * 1024, dc1 = dc0 + 512;

    const unsigned short* Ab = h + (size_t)(by * 256) * FF_DIM;   // chunk-relative packed rows
    const unsigned short* aptr0 = Ab + (size_t)row0 * FF_DIM + kc + kbase;
    const unsigned short* aptr1 = Ab + (size_t)(row0 + 16) * FF_DIM + kc + kbase;
    const unsigned short* Bb = wdt + (size_t)e * (C_DIM * FF_DIM) + (size_t)(bx * 256) * FF_DIM;
    const unsigned short* bptr0 = Bb + (size_t)row0 * FF_DIM + kc + kbase;
    const unsigned short* bptr1 = Bb + (size_t)(row0 + 16) * FF_DIM + kc + kbase;

    const int q8 = (4 * lrow + (lkq ^ ((lrow >> 1) & 3))) * 8;
    const int rdA = wm * 4096 + q8;
    const int rdB = wn * 2048 + q8;

    f32x4 acc[8][4] = {};
    bf16x8 af[2][4], bv[2][4];

    STG_A(0, 0);
    STG_B(1, 0);
    STG_A(2, 32);
    STG_B(3, 32);
    STG_A(4, 64);
    STG_B(5, 64);
    WAITV(4);
    BAR();
    LDAL(0, 0);
    LDB_(0, 1);

    #pragma unroll 1
    for (int i = 0; i < ni - 1; ++i) {
        const int kb = 128 * i;
        ITER8H(kb);
    }
    ITER8H_LAST(128 * (ni - 1));

    // epilogue: partial[p][col] = cwg[p] * acc (pads have cwg=0; rows unread)
    #pragma unroll
    for (int mi = 0; mi < 8; ++mi) {
        int pb = p0 + wm * 128 + mi * 16 + lkq * 4;
        float w4[4];
        #pragma unroll
        for (int r = 0; r < 4; ++r) w4[r] = cwg[pb + r];
        #pragma unroll
        for (int ni_ = 0; ni_ < 4; ++ni_) {
            int col = bx * 256 + wn * 64 + ni_ * 16 + lrow;
            f32x4 a = acc[mi][ni_];
            #pragma unroll
            for (int r = 0; r < 4; ++r) {
                float v = w4[r] * a[r];
                if (F32OUT)
                    yd32[(size_t)kz * PLANE_E + (size_t)(pb + r) * C_DIM + col] = v;
                else
                    yd[(size_t)(pb + r) * C_DIM + col] = f2bf(v);
            }
        }
    }
}

// ---------------- combine (legacy bf16 path): out[t] = yd[slotA] + yd[slotB] ----------------
__global__ void k_combine(const unsigned short* __restrict__ yd, const int* __restrict__ pos2,
                          float* __restrict__ out) {
    int t = blockIdx.x;
    int c4 = threadIdx.x * 4;
    int pA = pos2[t * 2], pB = pos2[t * 2 + 1];
    ushort4 a = *(const ushort4*)(yd + (size_t)pA * C_DIM + c4);
    ushort4 b = *(const ushort4*)(yd + (size_t)pB * C_DIM + c4);
    float4 o;
    o.x = bf2f(a.x) + bf2f(b.x);
    o.y = bf2f(a.y) + bf2f(b.y);
    o.z = bf2f(a.z) + bf2f(b.z);
    o.w = bf2f(a.w) + bf2f(b.w);
    *(float4*)(out + (size_t)t * C_DIM + c4) = o;
}

// ---------------- combine (K-split path): out[t] = sum over 2 slots x 2 f32 planes ----------------
__global__ void k_combine2(const float* __restrict__ yd32, const int* __restrict__ pos2,
                           float* __restrict__ out) {
    int t = blockIdx.x;
    int c4 = threadIdx.x * 4;
    int pA = pos2[t * 2], pB = pos2[t * 2 + 1];
    const float4* a0 = (const float4*)(yd32 + (size_t)pA * C_DIM + c4);
    const float4* a1 = (const float4*)(yd32 + (size_t)PLANE_E + (size_t)pA * C_DIM + c4);
    const float4* b0 = (const float4*)(yd32 + (size_t)pB * C_DIM + c4);
    const float4* b1 = (const float4*)(yd32 + (size_t)PLANE_E + (size_t)pB * C_DIM + c4);
    float4 va0 = *a0, va1 = *a1, vb0 = *b0, vb1 = *b1;
    float4 o;
    o.x = (va0.x + va1.x) + (vb0.x + vb1.x);
    o.y = (va0.y + va1.y) + (vb0.y + vb1.y);
    o.z = (va0.z + va1.z) + (vb0.z + vb1.z);
    o.w = (va0.w + va1.w) + (vb0.w + vb1.w);
    *(float4*)(out + (size_t)t * C_DIM + c4) = o;
}

extern "C" void kernel_launch(void* const* d_in, const int* in_sizes, int n_in,
                              void* d_out, int out_size, void* d_ws, size_t ws_size,
                              hipStream_t stream) {
    (void)in_sizes; (void)n_in; (void)out_size;
    const float* x   = (const float*)d_in[0];
    const float* w_r = (const float*)d_in[1];
    const float* w_g = (const float*)d_in[2];
    const float* w_u = (const float*)d_in[3];
    const float* w_d = (const float*)d_in[4];
    float* out = (float*)d_out;

    char* ws = (char*)d_ws;
    unsigned short* xb   = (unsigned short*)(ws);                    // 16,777,216
    unsigned short* wgut = (unsigned short*)(ws + 16777216);         // 67,108,864
    unsigned short* wdt  = (unsigned short*)(ws + 83886080);         // 33,554,432
    unsigned short* yd   = (unsigned short*)(ws + 117440512);        // 35,651,584 (17408 x 1024)
    float*          cw   = (float*)(ws + 153092096);                 //    131,072
    int*            rowlist = (int*)(ws + 153223168);                //     69,632
    float*          cwg  = (float*)(ws + 153292800);                 //     69,632
    int*            pos2 = (int*)(ws + 153362432);                   //     65,536
    int*            meta = (int*)(ws + 153427968);                   //        512
    unsigned short* h    = (unsigned short*)(ws + 153428480);        // chunked: 2 MiB / 256-row block

    const size_t H_OFF   = 153428480;
    const size_t H_FULL  = (size_t)TOTB256 * 256 * FF_DIM * 2;       // 142,606,336
    const size_t PLANE_B = (size_t)PLANE_E * 4;                      //  71,303,168
    // K-split path needs full h + two f32 partial planes
    const int split = (ws_size >= H_OFF + H_FULL + 2 * PLANE_B) ? 1 : 0;
    float* yd32 = (float*)(ws + H_OFF + H_FULL);

    hipFuncSetAttribute((const void*)k_gateup, hipFuncAttributeMaxDynamicSharedMemorySize, 8 * SLOT_E * 2);
    hipFuncSetAttribute((const void*)k_down<1>, hipFuncAttributeMaxDynamicSharedMemorySize, 8 * SLOT_E * 2);
    hipFuncSetAttribute((const void*)k_down<0>, hipFuncAttributeMaxDynamicSharedMemorySize, 8 * SLOT_E * 2);

    k_router<<<N_TOK / 4, 256, 0, stream>>>(x, w_r, cw, xb);
    k_build<<<1, 256, 0, stream>>>(cw, rowlist, cwg, pos2, meta);

    k_tconv<<<dim3(FF_DIM / 64, C_DIM / 64, NE), 256, 0, stream>>>(w_g, wgut, C_DIM, FF_DIM, (size_t)2 * C_DIM * FF_DIM, 1, 0);
    k_tconv<<<dim3(FF_DIM / 64, C_DIM / 64, NE), 256, 0, stream>>>(w_u, wgut, C_DIM, FF_DIM, (size_t)2 * C_DIM * FF_DIM, 1, 16);
    k_tconv<<<dim3(C_DIM / 64, FF_DIM / 64, NE), 256, 0, stream>>>(w_d, wdt, FF_DIM, C_DIM, (size_t)C_DIM * FF_DIM, 0, 0);

    if (split) {
        // full-size h guaranteed by the split space check
        k_gateup<<<dim3(2 * FF_DIM / 256, TOTB256), 512, 8 * SLOT_E * 2, stream>>>(xb, wgut, rowlist, meta, h, 0);
        k_down<1><<<dim3(C_DIM / 256, TOTB256, 2), 512, 8 * SLOT_E * 2, stream>>>(h, wdt, cwg, meta, yd, yd32, 0, FF_DIM / 256);
        k_combine2<<<N_TOK, 256, 0, stream>>>(yd32, pos2, out);
    } else {
        size_t h_avail = ws_size > H_OFF ? ws_size - H_OFF : 0;
        int maxb = (int)(h_avail / (256 * FF_DIM * 2));   // 2 MiB per 256-row block
        if (maxb < 1) maxb = 1;
        if (maxb > TOTB256) maxb = TOTB256;
        int nch = (TOTB256 + maxb - 1) / maxb;
        for (int c = 0; c < nch; ++c) {
            int cb = c * maxb;
            int nb = (TOTB256 - cb) < maxb ? (TOTB256 - cb) : maxb;
            k_gateup<<<dim3(2 * FF_DIM / 256, nb), 512, 8 * SLOT_E * 2, stream>>>(xb, wgut, rowlist, meta, h, cb * 256);
            k_down<0><<<dim3(C_DIM / 256, nb, 1), 512, 8 * SLOT_E * 2, stream>>>(h, wdt, cwg, meta, yd, yd32, cb * 256, FF_DIM / 128);
        }
        k_combine<<<N_TOK, 256, 0, stream>>>(yd, pos2, out);
    }
}

// Round 11
// 622.445 us; speedup vs baseline: 1.0248x; 1.0248x over previous
//
#include <hip/hip_runtime.h>
#include <hip/hip_bf16.h>

#define N_TOK 8192
#define C_DIM 1024
#define FF_DIM 4096
#define NE 4
#define ROWS_MAX 17408           // max padded packed rows (16384 + 4*256 slack)
#define TOTB256 68               // ROWS_MAX / 256

typedef __attribute__((ext_vector_type(8))) short bf16x8;
typedef __attribute__((ext_vector_type(4))) float f32x4;

__device__ __forceinline__ unsigned short f2bf(float f) {
    union { float f; unsigned int u; } v; v.f = f;
    return (unsigned short)((v.u + 0x7FFFu + ((v.u >> 16) & 1u)) >> 16);
}
__device__ __forceinline__ float bf2f(unsigned short u) {
    union { unsigned int u; float f; } v; v.u = ((unsigned int)u) << 16;
    return v.f;
}

__device__ __forceinline__ void gload_lds16(const void* g, void* l) {
    __builtin_amdgcn_global_load_lds(
        (const __attribute__((address_space(1))) unsigned int*)g,
        (__attribute__((address_space(3))) unsigned int*)l, 16, 0, 0);
}

#define WAITV(N) do { asm volatile("s_waitcnt vmcnt(" #N ")" ::: "memory"); __builtin_amdgcn_sched_barrier(0); } while (0)
#define WAITL0()  do { asm volatile("s_waitcnt lgkmcnt(0)" ::: "memory"); __builtin_amdgcn_sched_barrier(0); } while (0)
#define BAR()     do { __builtin_amdgcn_s_barrier(); __builtin_amdgcn_sched_barrier(0); } while (0)
#define PRIO1()   __builtin_amdgcn_s_setprio(1)
#define PRIO0()   __builtin_amdgcn_s_setprio(0)

// bijective XCD-aware block swizzle (m204): contiguous id-chunks per XCD (k_down)
__device__ __forceinline__ int2 xcd_swz(int gx, int gy) {
    int wg = blockIdx.y * gx + blockIdx.x;
    int nwg = gx * gy;
    int q = nwg >> 3, r = nwg & 7;
    int xcd = wg & 7, idx = wg >> 3;
    int swz = (xcd < r) ? (xcd * (q + 1) + idx) : (r * (q + 1) + (xcd - r) * q + idx);
    return make_int2(swz % gx, swz / gx);
}

// gateup strip swizzle (gx==32 only): each XCD owns a 4-bx column strip; its 32
// concurrent blocks form 4bx x 8by -> B working set L2-resident.
__device__ __forceinline__ int2 strip_swz32() {
    int wg = blockIdx.y * 32 + blockIdx.x;
    int xcd = wg & 7, idx = wg >> 3;
    int bx = xcd * 4 + (idx & 3);
    int by = (idx >> 4) * 4 + ((idx >> 2) & 3);
    return make_int2(bx, by);
}

// ------- transpose+convert: src fp32 [z][R][S] -> dst bf16 [z][S][R]
__global__ void k_tconv(const float* __restrict__ src0, unsigned short* __restrict__ dst0,
                        int R, int S, size_t dz, int perm, int guoff) {
    __shared__ float tile[64][65];
    const float* src = src0 + (size_t)blockIdx.z * R * S;
    unsigned short* dst = dst0 + (size_t)blockIdx.z * dz;
    const int tc = blockIdx.x * 64;
    const int tr = blockIdx.y * 64;
    const int tid = threadIdx.x;
    const int lr = tid >> 4;          // 0..15
    const int lc4 = (tid & 15) * 4;   // 0..60
    #pragma unroll
    for (int i = 0; i < 64; i += 16) {
        float4 v = *(const float4*)(src + (size_t)(tr + lr + i) * S + tc + lc4);
        tile[lr + i][lc4 + 0] = v.x;
        tile[lr + i][lc4 + 1] = v.y;
        tile[lr + i][lc4 + 2] = v.z;
        tile[lr + i][lc4 + 3] = v.w;
    }
    __syncthreads();
    const int oc = tid >> 4;          // 0..15
    const int r4 = (tid & 15) * 4;    // 0..60
    #pragma unroll
    for (int i = 0; i < 64; i += 16) {
        int cp = tc + oc + i;
        int rowo = perm ? (32 * (cp >> 4) + (cp & 15) + guoff) : cp;
        ushort4 o;
        o.x = f2bf(tile[r4 + 0][oc + i]);
        o.y = f2bf(tile[r4 + 1][oc + i]);
        o.z = f2bf(tile[r4 + 2][oc + i]);
        o.w = f2bf(tile[r4 + 3][oc + i]);
        *(ushort4*)(dst + (size_t)rowo * R + tr + r4) = o;
    }
}

// ---------------- router: fp32 logits, softmax, top-2 -> cw[N][4]; also emits xb ----------------
__global__ void k_router(const float* __restrict__ x, const float* __restrict__ wr,
                         float* __restrict__ cw, unsigned short* __restrict__ xb) {
    int wv = threadIdx.x >> 6, lane = threadIdx.x & 63;
    int n = blockIdx.x * 4 + wv;
    const float* xr = x + (size_t)n * C_DIM;
    unsigned short* xbr = xb + (size_t)n * C_DIM;
    const float4* wr4 = (const float4*)wr;
    float p0 = 0.f, p1 = 0.f, p2 = 0.f, p3 = 0.f;
    for (int j = 0; j < C_DIM / 64; ++j) {
        int c = j * 64 + lane;
        float xv = xr[c];
        xbr[c] = f2bf(xv);
        float4 w = wr4[c];
        p0 += xv * w.x; p1 += xv * w.y; p2 += xv * w.z; p3 += xv * w.w;
    }
    #pragma unroll
    for (int off = 32; off > 0; off >>= 1) {
        p0 += __shfl_down(p0, off);
        p1 += __shfl_down(p1, off);
        p2 += __shfl_down(p2, off);
        p3 += __shfl_down(p3, off);
    }
    if (lane == 0) {
        float l[NE] = {p0, p1, p2, p3};
        float mx = fmaxf(fmaxf(l[0], l[1]), fmaxf(l[2], l[3]));
        float e0[NE]; float s = 0.f;
        #pragma unroll
        for (int i = 0; i < NE; ++i) { e0[i] = expf(l[i] - mx); s += e0[i]; }
        #pragma unroll
        for (int i = 0; i < NE; ++i) e0[i] /= s;
        int i1 = 0;
        #pragma unroll
        for (int i = 1; i < NE; ++i) if (e0[i] > e0[i1]) i1 = i;
        int i2 = -1;
        #pragma unroll
        for (int i = 0; i < NE; ++i) { if (i == i1) continue; if (i2 < 0 || e0[i] > e0[i2]) i2 = i; }
        float o[NE] = {0.f, 0.f, 0.f, 0.f};
        o[i1] = e0[i1]; o[i2] = e0[i2];
        *(float4*)(cw + (size_t)n * 4) = make_float4(o[0], o[1], o[2], o[3]);
    }
}

// ---------------- build per-expert token lists (deterministic, token-id order) ----------------
__global__ void k_build(const float* __restrict__ cw, int* __restrict__ rowlist,
                        float* __restrict__ cwg, int* __restrict__ pos2, int* __restrict__ meta) {
    __shared__ int lcnt[256][NE];
    int tid = threadIdx.x;
    int t0 = tid * 32;
    int c[NE] = {0, 0, 0, 0};
    for (int i = 0; i < 32; ++i) {
        const float* w = cw + (size_t)(t0 + i) * NE;
        #pragma unroll
        for (int e = 0; e < NE; ++e) if (w[e] > 0.f) c[e]++;
    }
    #pragma unroll
    for (int e = 0; e < NE; ++e) lcnt[tid][e] = c[e];
    __syncthreads();
    if (tid == 0) {
        int tot[NE] = {0, 0, 0, 0};
        for (int i = 0; i < 256; ++i)
            #pragma unroll
            for (int e = 0; e < NE; ++e) { int v = lcnt[i][e]; lcnt[i][e] = tot[e]; tot[e] += v; }
        int off = 0;
        #pragma unroll
        for (int e = 0; e < NE; ++e) {
            meta[e] = tot[e];
            int p = (tot[e] + 255) & ~255;
            meta[4 + e] = p;
            meta[8 + e] = off;
            off += p;
        }
        meta[12] = off;
    }
    __syncthreads();
    int pos[NE];
    #pragma unroll
    for (int e = 0; e < NE; ++e) pos[e] = lcnt[tid][e];
    for (int i = 0; i < 32; ++i) {
        int t = t0 + i;
        const float* w = cw + (size_t)t * NE;
        int sl = 0;
        #pragma unroll
        for (int e = 0; e < NE; ++e) if (w[e] > 0.f) {
            int p = meta[8 + e] + pos[e]++;
            rowlist[p] = t;
            cwg[p] = w[e];
            pos2[t * 2 + sl] = p;
            sl++;
        }
    }
    __syncthreads();
    if (tid < NE) {
        int e = tid;
        for (int p = meta[e]; p < meta[4 + e]; ++p) {
            rowlist[meta[8 + e] + p] = 0;
            cwg[meta[8 + e] + p] = 0.f;
        }
    }
}

// ================= 8-phase full-hoist 256x256 core — SINGLE barrier per phase =================
// R8 core (coalesced staging R6, conflict-free read swizzle R7, all reads in
// MFMA windows) with the trailing per-phase barrier DELETED: 8 barriers/iter
// instead of 16. Safety audit (1-barrier phase = STAGE_p; BAR_p; lgkm0;
// [vmcnt]; window_p): a stage at phase p+1 must not touch slots read in
// window_p (unsynchronized, fast-wave hazard) or window_{p-1} (slow wave may
// hold in-flight reads until its WAITL0 after BAR_p). Stage targets vs read
// sets: ph1:7 vs {0}; ph2:0 vs {2,3}; ph3:1 vs {2}; ph4:2 vs {4,5}; ph5:3 vs
// {4}; ph6:4 vs {6,7}; ph7:5 vs {6}; ph0':6 vs {0,1} -> no collision; every
// slot still has >=1 barrier between last read-issue and restage-issue, the
// same guarantee the 2-barrier template provides. Counted-WAITV publish points
// unchanged (each confirms >=1 barrier before the dependent read). Data
// bit-identical.
#define SLOT_E 8192   // elems per unit slot

#define STAGE_U(P0, P1, slot, kofs) do { \
    gload_lds16((P0) + (kofs), smem + (slot) * SLOT_E + dc0); \
    gload_lds16((P1) + (kofs), smem + (slot) * SLOT_E + dc1); } while (0)
#define STG_A(slot, kofs) STAGE_U(aptr0, aptr1, slot, kofs)
#define STG_B(slot, kofs) STAGE_U(bptr0, bptr1, slot, kofs)

#define LDAL(bk, s) do { _Pragma("unroll") \
    for (int m_ = 0; m_ < 4; ++m_) af[bk][m_] = *(const bf16x8*)&smem[(s) * SLOT_E + rdA + m_ * 512]; } while (0)
#define LDAH(bk, s) do { _Pragma("unroll") \
    for (int m_ = 0; m_ < 4; ++m_) af[bk][m_] = *(const bf16x8*)&smem[(s) * SLOT_E + rdA + (4 + m_) * 512]; } while (0)
#define LDB_(bk, s) do { _Pragma("unroll") \
    for (int n_ = 0; n_ < 4; ++n_) bv[bk][n_] = *(const bf16x8*)&smem[(s) * SLOT_E + rdB + n_ * 512]; } while (0)

#define MMLO(ab, bb) do { _Pragma("unroll") \
    for (int m_ = 0; m_ < 4; ++m_) \
        _Pragma("unroll") \
        for (int n_ = 0; n_ < 4; ++n_) \
            acc[m_][n_] = __builtin_amdgcn_mfma_f32_16x16x32_bf16(af[ab][m_], bv[bb][n_], acc[m_][n_], 0, 0, 0); } while (0)
#define MMHI(ab, bb) do { _Pragma("unroll") \
    for (int m_ = 0; m_ < 4; ++m_) \
        _Pragma("unroll") \
        for (int n_ = 0; n_ < 4; ++n_) \
            acc[4 + m_][n_] = __builtin_amdgcn_mfma_f32_16x16x32_bf16(af[ab][m_], bv[bb][n_], acc[4 + m_][n_], 0, 0, 0); } while (0)

// Steady-state iteration: one barrier per phase; ph7 pre-reads next ph0.
#define ITER8H(kb) do { \
    /* ph0 */ STG_A(6, (kb) + 96);  BAR(); WAITL0();           PRIO1(); LDAH(1, 0);              MMLO(0, 0); PRIO0(); \
    /* ph1 */ STG_B(7, (kb) + 96);  BAR(); WAITL0();           PRIO1(); LDAL(0, 2); LDB_(1, 3);  MMHI(1, 0); PRIO0(); \
    /* ph2 */ STG_A(0, (kb) + 128); BAR(); WAITL0(); WAITV(6); PRIO1(); LDAH(1, 2);              MMLO(0, 1); PRIO0(); \
    /* ph3 */ STG_B(1, (kb) + 128); BAR(); WAITL0();           PRIO1(); LDAL(0, 4); LDB_(0, 5);  MMHI(1, 1); PRIO0(); \
    /* ph4 */ STG_A(2, (kb) + 160); BAR(); WAITL0(); WAITV(4); PRIO1(); LDAH(1, 4);              MMLO(0, 0); PRIO0(); \
    /* ph5 */ STG_B(3, (kb) + 160); BAR(); WAITL0();           PRIO1(); LDAL(0, 6); LDB_(1, 7);  MMHI(1, 0); PRIO0(); \
    /* ph6 */ STG_A(4, (kb) + 192); BAR(); WAITL0(); WAITV(6); PRIO1(); LDAH(1, 6);              MMLO(0, 1); PRIO0(); \
    /* ph7 */ STG_B(5, (kb) + 192); BAR(); WAITL0(); WAITV(4); PRIO1(); LDAL(0, 0); LDB_(0, 1);  MMHI(1, 1); PRIO0(); \
} while (0)

// Last iteration: only kb+96 half-tile staged; waits adjusted; no ph7 pre-read.
#define ITER8H_LAST(kb) do { \
    STG_A(6, (kb) + 96); BAR(); WAITL0();           PRIO1(); LDAH(1, 0);              MMLO(0, 0); PRIO0(); \
    STG_B(7, (kb) + 96); BAR(); WAITL0();           PRIO1(); LDAL(0, 2); LDB_(1, 3);  MMHI(1, 0); PRIO0(); \
                         BAR(); WAITL0(); WAITV(4); PRIO1(); LDAH(1, 2);              MMLO(0, 1); PRIO0(); \
                         BAR(); WAITL0();           PRIO1(); LDAL(0, 4); LDB_(0, 5);  MMHI(1, 1); PRIO0(); \
                         BAR(); WAITL0(); WAITV(0); PRIO1(); LDAH(1, 4);              MMLO(0, 0); PRIO0(); \
                         BAR(); WAITL0();           PRIO1(); LDAL(0, 6); LDB_(1, 7);  MMHI(1, 0); PRIO0(); \
                         BAR(); WAITL0();           PRIO1(); LDAH(1, 6);              MMLO(0, 1); PRIO0(); \
                         BAR(); WAITL0();           PRIO1();                          MMHI(1, 1); PRIO0(); \
} while (0)

// ---------------- merged gate+up GEMM (gathered A rows), silu epilogue ----------------
__global__ __launch_bounds__(512, 1) void k_gateup(
    const unsigned short* __restrict__ xb,
    const unsigned short* __restrict__ wgut,
    const int* __restrict__ rowlist,
    const int* __restrict__ meta,
    unsigned short* __restrict__ h,
    int cbase)
{
    extern __shared__ unsigned short smem[];
    int2 sb = strip_swz32();
    const int bx = sb.x, by = sb.y;
    const int p0 = cbase + by * 256;
    if (p0 >= meta[12]) return;
    const int e = (p0 >= meta[9]) + (p0 >= meta[10]) + (p0 >= meta[11]);

    const int tid = threadIdx.x;
    const int wid = tid >> 6, lane = tid & 63;
    const int wm = wid >> 2, wn = wid & 3;
    const int lrow = lane & 15, lkq = lane >> 4;

    // coalesced staging: inst j of wave wid covers rows 32*wid+16*j..+15;
    // lane l -> row +(l>>2), chunk (l&3)^((l>>3)&3) (quad = one 64B line).
    const int lsub = lane >> 2;                        // 0..15
    const int kc = ((lane & 3) ^ ((lane >> 3) & 3)) * 8;
    const int row0 = 32 * wid + lsub;
    const int dc0 = wid * 1024, dc1 = dc0 + 512;       // linear dest

    const unsigned short* aptr0 = xb + (size_t)rowlist[p0 + row0] * C_DIM + kc;
    const unsigned short* aptr1 = xb + (size_t)rowlist[p0 + row0 + 16] * C_DIM + kc;
    const unsigned short* Bb = wgut + (size_t)e * (2 * C_DIM * FF_DIM) + (size_t)(bx * 256) * C_DIM;
    const unsigned short* bptr0 = Bb + (size_t)row0 * C_DIM + kc;
    const unsigned short* bptr1 = Bb + (size_t)(row0 + 16) * C_DIM + kc;

    // read side: granule (row>>4)*512 elems; q = 4*lrow + (lkq ^ ((lrow>>1)&3))
    const int q8 = (4 * lrow + (lkq ^ ((lrow >> 1) & 3))) * 8;
    const int rdA = wm * 4096 + q8;    // granule base wm*8 * 512
    const int rdB = wn * 2048 + q8;    // granule base wn*4 * 512

    f32x4 acc[8][4] = {};
    bf16x8 af[2][4], bv[2][4];

    STG_A(0, 0);
    STG_B(1, 0);
    STG_A(2, 32);
    STG_B(3, 32);
    STG_A(4, 64);
    STG_B(5, 64);
    WAITV(4);          // confirms slots 0..3; {4,5} in flight
    BAR();
    LDAL(0, 0);        // prologue pre-read for ph0
    LDB_(0, 1);

    const int NI = C_DIM / 128;            // 8
    #pragma unroll 1
    for (int i = 0; i < NI - 1; ++i) {
        const int kb = 128 * i;
        ITER8H(kb);
    }
    ITER8H_LAST(128 * (NI - 1));

    // epilogue: h = silu(gate) * up
    const int ffb = bx * 128 + wn * 32;
    #pragma unroll
    for (int mi = 0; mi < 8; ++mi) {
        int row = by * 256 + wm * 128 + mi * 16 + lkq * 4;   // chunk-relative h row
        #pragma unroll
        for (int j = 0; j < 2; ++j) {
            int ff = ffb + 16 * j + lrow;
            f32x4 g = acc[mi][2 * j];
            f32x4 u = acc[mi][2 * j + 1];
            #pragma unroll
            for (int r = 0; r < 4; ++r) {
                float gv = g[r];
                float hv = gv / (1.f + __expf(-gv)) * u[r];
                h[(size_t)(row + r) * FF_DIM + ff] = f2bf(hv);
            }
        }
    }
}

// ---------------- down GEMM, same single-barrier core: yd[p] = cwg[p] * (h @ wd[e]) ----------------
__global__ __launch_bounds__(512, 1) void k_down(
    const unsigned short* __restrict__ h,
    const unsigned short* __restrict__ wdt,
    const float* __restrict__ cwg,
    const int* __restrict__ meta,
    unsigned short* __restrict__ yd,
    int cbase)
{
    extern __shared__ unsigned short smem[];
    int2 sb = xcd_swz(gridDim.x, gridDim.y);
    const int bx = sb.x, by = sb.y;
    const int p0 = cbase + by * 256;
    if (p0 >= meta[12]) return;
    const int e = (p0 >= meta[9]) + (p0 >= meta[10]) + (p0 >= meta[11]);

    const int tid = threadIdx.x;
    const int wid = tid >> 6, lane = tid & 63;
    const int wm = wid >> 2, wn = wid & 3;
    const int lrow = lane & 15, lkq = lane >> 4;

    const int lsub = lane >> 2;
    const int kc = ((lane & 3) ^ ((lane >> 3) & 3)) * 8;
    const int row0 = 32 * wid + lsub;
    const int dc0 = wid * 1024, dc1 = dc0 + 512;

    const unsigned short* Ab = h + (size_t)(by * 256) * FF_DIM;   // chunk-relative packed rows
    const unsigned short* aptr0 = Ab + (size_t)row0 * FF_DIM + kc;
    const unsigned short* aptr1 = Ab + (size_t)(row0 + 16) * FF_DIM + kc;
    const unsigned short* Bb = wdt + (size_t)e * (C_DIM * FF_DIM) + (size_t)(bx * 256) * FF_DIM;
    const unsigned short* bptr0 = Bb + (size_t)row0 * FF_DIM + kc;
    const unsigned short* bptr1 = Bb + (size_t)(row0 + 16) * FF_DIM + kc;

    const int q8 = (4 * lrow + (lkq ^ ((lrow >> 1) & 3))) * 8;
    const int rdA = wm * 4096 + q8;
    const int rdB = wn * 2048 + q8;

    f32x4 acc[8][4] = {};
    bf16x8 af[2][4], bv[2][4];

    STG_A(0, 0);
    STG_B(1, 0);
    STG_A(2, 32);
    STG_B(3, 32);
    STG_A(4, 64);
    STG_B(5, 64);
    WAITV(4);
    BAR();
    LDAL(0, 0);
    LDB_(0, 1);

    const int NI = FF_DIM / 128;           // 32
    #pragma unroll 1
    for (int i = 0; i < NI - 1; ++i) {
        const int kb = 128 * i;
        ITER8H(kb);
    }
    ITER8H_LAST(128 * (NI - 1));

    // epilogue: yd[p][col] = cwg[p] * acc (pads have cwg=0; rows unread)
    #pragma unroll
    for (int mi = 0; mi < 8; ++mi) {
        int pb = p0 + wm * 128 + mi * 16 + lkq * 4;
        float w4[4];
        #pragma unroll
        for (int r = 0; r < 4; ++r) w4[r] = cwg[pb + r];
        #pragma unroll
        for (int ni = 0; ni < 4; ++ni) {
            int col = bx * 256 + wn * 64 + ni * 16 + lrow;
            f32x4 a = acc[mi][ni];
            #pragma unroll
            for (int r = 0; r < 4; ++r)
                yd[(size_t)(pb + r) * C_DIM + col] = f2bf(w4[r] * a[r]);
        }
    }
}

// ---------------- combine: out[t] = yd[slotA] + yd[slotB] (deterministic) ----------------
__global__ void k_combine(const unsigned short* __restrict__ yd, const int* __restrict__ pos2,
                          float* __restrict__ out) {
    int t = blockIdx.x;
    int c4 = threadIdx.x * 4;
    int pA = pos2[t * 2], pB = pos2[t * 2 + 1];
    ushort4 a = *(const ushort4*)(yd + (size_t)pA * C_DIM + c4);
    ushort4 b = *(const ushort4*)(yd + (size_t)pB * C_DIM + c4);
    float4 o;
    o.x = bf2f(a.x) + bf2f(b.x);
    o.y = bf2f(a.y) + bf2f(b.y);
    o.z = bf2f(a.z) + bf2f(b.z);
    o.w = bf2f(a.w) + bf2f(b.w);
    *(float4*)(out + (size_t)t * C_DIM + c4) = o;
}

extern "C" void kernel_launch(void* const* d_in, const int* in_sizes, int n_in,
                              void* d_out, int out_size, void* d_ws, size_t ws_size,
                              hipStream_t stream) {
    (void)in_sizes; (void)n_in; (void)out_size;
    const float* x   = (const float*)d_in[0];
    const float* w_r = (const float*)d_in[1];
    const float* w_g = (const float*)d_in[2];
    const float* w_u = (const float*)d_in[3];
    const float* w_d = (const float*)d_in[4];
    float* out = (float*)d_out;

    char* ws = (char*)d_ws;
    unsigned short* xb   = (unsigned short*)(ws);                    // 16,777,216
    unsigned short* wgut = (unsigned short*)(ws + 16777216);         // 67,108,864
    unsigned short* wdt  = (unsigned short*)(ws + 83886080);         // 33,554,432
    unsigned short* yd   = (unsigned short*)(ws + 117440512);        // 35,651,584 (17408 x 1024)
    float*          cw   = (float*)(ws + 153092096);                 //    131,072
    int*            rowlist = (int*)(ws + 153223168);                //     69,632
    float*          cwg  = (float*)(ws + 153292800);                 //     69,632
    int*            pos2 = (int*)(ws + 153362432);                   //     65,536
    int*            meta = (int*)(ws + 153427968);                   //        512
    unsigned short* h    = (unsigned short*)(ws + 153428480);        // chunked: 2 MiB / 256-row block

    hipFuncSetAttribute((const void*)k_gateup, hipFuncAttributeMaxDynamicSharedMemorySize, 8 * SLOT_E * 2);
    hipFuncSetAttribute((const void*)k_down,   hipFuncAttributeMaxDynamicSharedMemorySize, 8 * SLOT_E * 2);

    size_t h_avail = ws_size > 153428480 ? ws_size - 153428480 : 0;
    int maxb = (int)(h_avail / (256 * FF_DIM * 2));   // 2 MiB per 256-row block
    if (maxb < 1) maxb = 1;
    if (maxb > TOTB256) maxb = TOTB256;
    int nch = (TOTB256 + maxb - 1) / maxb;

    k_router<<<N_TOK / 4, 256, 0, stream>>>(x, w_r, cw, xb);
    k_build<<<1, 256, 0, stream>>>(cw, rowlist, cwg, pos2, meta);

    k_tconv<<<dim3(FF_DIM / 64, C_DIM / 64, NE), 256, 0, stream>>>(w_g, wgut, C_DIM, FF_DIM, (size_t)2 * C_DIM * FF_DIM, 1, 0);
    k_tconv<<<dim3(FF_DIM / 64, C_DIM / 64, NE), 256, 0, stream>>>(w_u, wgut, C_DIM, FF_DIM, (size_t)2 * C_DIM * FF_DIM, 1, 16);
    k_tconv<<<dim3(C_DIM / 64, FF_DIM / 64, NE), 256, 0, stream>>>(w_d, wdt, FF_DIM, C_DIM, (size_t)C_DIM * FF_DIM, 0, 0);

    for (int c = 0; c < nch; ++c) {
        int cb = c * maxb;
        int nb = (TOTB256 - cb) < maxb ? (TOTB256 - cb) : maxb;
        k_gateup<<<dim3(2 * FF_DIM / 256, nb), 512, 8 * SLOT_E * 2, stream>>>(xb, wgut, rowlist, meta, h, cb * 256);
        k_down<<<dim3(C_DIM / 256, nb), 512, 8 * SLOT_E * 2, stream>>>(h, wdt, cwg, meta, yd, cb * 256);
    }
    k_combine<<<N_TOK, 256, 0, stream>>>(yd, pos2, out);
}

// Round 12
// 622.222 us; speedup vs baseline: 1.0252x; 1.0004x over previous
//
#include <hip/hip_runtime.h>
#include <hip/hip_bf16.h>

#define N_TOK 8192
#define C_DIM 1024
#define FF_DIM 4096
#define NE 4
#define ROWS_MAX 17408           // max padded packed rows (16384 + 4*256 slack)
#define TOTB256 68               // ROWS_MAX / 256
#define SPLIT_P0 16384           // rows below: full-K path; at/above: 4-way K-split tail
#define PART_PLANE 1048576       // 1024 rows x 1024 cols (f32 elems per tail plane)

typedef __attribute__((ext_vector_type(8))) short bf16x8;
typedef __attribute__((ext_vector_type(4))) float f32x4;

__device__ __forceinline__ unsigned short f2bf(float f) {
    union { float f; unsigned int u; } v; v.f = f;
    return (unsigned short)((v.u + 0x7FFFu + ((v.u >> 16) & 1u)) >> 16);
}
__device__ __forceinline__ float bf2f(unsigned short u) {
    union { unsigned int u; float f; } v; v.u = ((unsigned int)u) << 16;
    return v.f;
}

__device__ __forceinline__ void gload_lds16(const void* g, void* l) {
    __builtin_amdgcn_global_load_lds(
        (const __attribute__((address_space(1))) unsigned int*)g,
        (__attribute__((address_space(3))) unsigned int*)l, 16, 0, 0);
}

#define WAITV(N) do { asm volatile("s_waitcnt vmcnt(" #N ")" ::: "memory"); __builtin_amdgcn_sched_barrier(0); } while (0)
#define WAITL0()  do { asm volatile("s_waitcnt lgkmcnt(0)" ::: "memory"); __builtin_amdgcn_sched_barrier(0); } while (0)
#define BAR()     do { __builtin_amdgcn_s_barrier(); __builtin_amdgcn_sched_barrier(0); } while (0)
#define PRIO1()   __builtin_amdgcn_s_setprio(1)
#define PRIO0()   __builtin_amdgcn_s_setprio(0)

// bijective XCD-aware block swizzle (m204): contiguous id-chunks per XCD (k_down)
__device__ __forceinline__ int2 xcd_swz(int gx, int gy) {
    int wg = blockIdx.y * gx + blockIdx.x;
    int nwg = gx * gy;
    int q = nwg >> 3, r = nwg & 7;
    int xcd = wg & 7, idx = wg >> 3;
    int swz = (xcd < r) ? (xcd * (q + 1) + idx) : (r * (q + 1) + (xcd - r) * q + idx);
    return make_int2(swz % gx, swz / gx);
}

// gateup strip swizzle (gx==32 only): each XCD owns a 4-bx column strip; its 32
// concurrent blocks form 4bx x 8by -> B working set L2-resident.
__device__ __forceinline__ int2 strip_swz32() {
    int wg = blockIdx.y * 32 + blockIdx.x;
    int xcd = wg & 7, idx = wg >> 3;
    int bx = xcd * 4 + (idx & 3);
    int by = (idx >> 4) * 4 + ((idx >> 2) & 3);
    return make_int2(bx, by);
}

// ------- transpose+convert: src fp32 [z][R][S] -> dst bf16 [z][S][R]
__global__ void k_tconv(const float* __restrict__ src0, unsigned short* __restrict__ dst0,
                        int R, int S, size_t dz, int perm, int guoff) {
    __shared__ float tile[64][65];
    const float* src = src0 + (size_t)blockIdx.z * R * S;
    unsigned short* dst = dst0 + (size_t)blockIdx.z * dz;
    const int tc = blockIdx.x * 64;
    const int tr = blockIdx.y * 64;
    const int tid = threadIdx.x;
    const int lr = tid >> 4;          // 0..15
    const int lc4 = (tid & 15) * 4;   // 0..60
    #pragma unroll
    for (int i = 0; i < 64; i += 16) {
        float4 v = *(const float4*)(src + (size_t)(tr + lr + i) * S + tc + lc4);
        tile[lr + i][lc4 + 0] = v.x;
        tile[lr + i][lc4 + 1] = v.y;
        tile[lr + i][lc4 + 2] = v.z;
        tile[lr + i][lc4 + 3] = v.w;
    }
    __syncthreads();
    const int oc = tid >> 4;          // 0..15
    const int r4 = (tid & 15) * 4;    // 0..60
    #pragma unroll
    for (int i = 0; i < 64; i += 16) {
        int cp = tc + oc + i;
        int rowo = perm ? (32 * (cp >> 4) + (cp & 15) + guoff) : cp;
        ushort4 o;
        o.x = f2bf(tile[r4 + 0][oc + i]);
        o.y = f2bf(tile[r4 + 1][oc + i]);
        o.z = f2bf(tile[r4 + 2][oc + i]);
        o.w = f2bf(tile[r4 + 3][oc + i]);
        *(ushort4*)(dst + (size_t)rowo * R + tr + r4) = o;
    }
}

// ---------------- router: fp32 logits, softmax, top-2 -> cw[N][4]; also emits xb ----------------
__global__ void k_router(const float* __restrict__ x, const float* __restrict__ wr,
                         float* __restrict__ cw, unsigned short* __restrict__ xb) {
    int wv = threadIdx.x >> 6, lane = threadIdx.x & 63;
    int n = blockIdx.x * 4 + wv;
    const float* xr = x + (size_t)n * C_DIM;
    unsigned short* xbr = xb + (size_t)n * C_DIM;
    const float4* wr4 = (const float4*)wr;
    float p0 = 0.f, p1 = 0.f, p2 = 0.f, p3 = 0.f;
    for (int j = 0; j < C_DIM / 64; ++j) {
        int c = j * 64 + lane;
        float xv = xr[c];
        xbr[c] = f2bf(xv);
        float4 w = wr4[c];
        p0 += xv * w.x; p1 += xv * w.y; p2 += xv * w.z; p3 += xv * w.w;
    }
    #pragma unroll
    for (int off = 32; off > 0; off >>= 1) {
        p0 += __shfl_down(p0, off);
        p1 += __shfl_down(p1, off);
        p2 += __shfl_down(p2, off);
        p3 += __shfl_down(p3, off);
    }
    if (lane == 0) {
        float l[NE] = {p0, p1, p2, p3};
        float mx = fmaxf(fmaxf(l[0], l[1]), fmaxf(l[2], l[3]));
        float e0[NE]; float s = 0.f;
        #pragma unroll
        for (int i = 0; i < NE; ++i) { e0[i] = expf(l[i] - mx); s += e0[i]; }
        #pragma unroll
        for (int i = 0; i < NE; ++i) e0[i] /= s;
        int i1 = 0;
        #pragma unroll
        for (int i = 1; i < NE; ++i) if (e0[i] > e0[i1]) i1 = i;
        int i2 = -1;
        #pragma unroll
        for (int i = 0; i < NE; ++i) { if (i == i1) continue; if (i2 < 0 || e0[i] > e0[i2]) i2 = i; }
        float o[NE] = {0.f, 0.f, 0.f, 0.f};
        o[i1] = e0[i1]; o[i2] = e0[i2];
        *(float4*)(cw + (size_t)n * 4) = make_float4(o[0], o[1], o[2], o[3]);
    }
}

// ---------------- build per-expert token lists (deterministic, token-id order) ----------------
__global__ void k_build(const float* __restrict__ cw, int* __restrict__ rowlist,
                        float* __restrict__ cwg, int* __restrict__ pos2, int* __restrict__ meta) {
    __shared__ int lcnt[256][NE];
    int tid = threadIdx.x;
    int t0 = tid * 32;
    int c[NE] = {0, 0, 0, 0};
    for (int i = 0; i < 32; ++i) {
        const float* w = cw + (size_t)(t0 + i) * NE;
        #pragma unroll
        for (int e = 0; e < NE; ++e) if (w[e] > 0.f) c[e]++;
    }
    #pragma unroll
    for (int e = 0; e < NE; ++e) lcnt[tid][e] = c[e];
    __syncthreads();
    if (tid == 0) {
        int tot[NE] = {0, 0, 0, 0};
        for (int i = 0; i < 256; ++i)
            #pragma unroll
            for (int e = 0; e < NE; ++e) { int v = lcnt[i][e]; lcnt[i][e] = tot[e]; tot[e] += v; }
        int off = 0;
        #pragma unroll
        for (int e = 0; e < NE; ++e) {
            meta[e] = tot[e];
            int p = (tot[e] + 255) & ~255;
            meta[4 + e] = p;
            meta[8 + e] = off;
            off += p;
        }
        meta[12] = off;
    }
    __syncthreads();
    int pos[NE];
    #pragma unroll
    for (int e = 0; e < NE; ++e) pos[e] = lcnt[tid][e];
    for (int i = 0; i < 32; ++i) {
        int t = t0 + i;
        const float* w = cw + (size_t)t * NE;
        int sl = 0;
        #pragma unroll
        for (int e = 0; e < NE; ++e) if (w[e] > 0.f) {
            int p = meta[8 + e] + pos[e]++;
            rowlist[p] = t;
            cwg[p] = w[e];
            pos2[t * 2 + sl] = p;
            sl++;
        }
    }
    __syncthreads();
    if (tid < NE) {
        int e = tid;
        for (int p = meta[e]; p < meta[4 + e]; ++p) {
            rowlist[meta[8 + e] + p] = 0;
            cwg[meta[8 + e] + p] = 0.f;
        }
    }
}

// ================= 8-phase full-hoist 256x256 core — single barrier per phase (R11) =================
#define SLOT_E 8192   // elems per unit slot

#define STAGE_U(P0, P1, slot, kofs) do { \
    gload_lds16((P0) + (kofs), smem + (slot) * SLOT_E + dc0); \
    gload_lds16((P1) + (kofs), smem + (slot) * SLOT_E + dc1); } while (0)
#define STG_A(slot, kofs) STAGE_U(aptr0, aptr1, slot, kofs)
#define STG_B(slot, kofs) STAGE_U(bptr0, bptr1, slot, kofs)

#define LDAL(bk, s) do { _Pragma("unroll") \
    for (int m_ = 0; m_ < 4; ++m_) af[bk][m_] = *(const bf16x8*)&smem[(s) * SLOT_E + rdA + m_ * 512]; } while (0)
#define LDAH(bk, s) do { _Pragma("unroll") \
    for (int m_ = 0; m_ < 4; ++m_) af[bk][m_] = *(const bf16x8*)&smem[(s) * SLOT_E + rdA + (4 + m_) * 512]; } while (0)
#define LDB_(bk, s) do { _Pragma("unroll") \
    for (int n_ = 0; n_ < 4; ++n_) bv[bk][n_] = *(const bf16x8*)&smem[(s) * SLOT_E + rdB + n_ * 512]; } while (0)

#define MMLO(ab, bb) do { _Pragma("unroll") \
    for (int m_ = 0; m_ < 4; ++m_) \
        _Pragma("unroll") \
        for (int n_ = 0; n_ < 4; ++n_) \
            acc[m_][n_] = __builtin_amdgcn_mfma_f32_16x16x32_bf16(af[ab][m_], bv[bb][n_], acc[m_][n_], 0, 0, 0); } while (0)
#define MMHI(ab, bb) do { _Pragma("unroll") \
    for (int m_ = 0; m_ < 4; ++m_) \
        _Pragma("unroll") \
        for (int n_ = 0; n_ < 4; ++n_) \
            acc[4 + m_][n_] = __builtin_amdgcn_mfma_f32_16x16x32_bf16(af[ab][m_], bv[bb][n_], acc[4 + m_][n_], 0, 0, 0); } while (0)

// Steady-state iteration: one barrier per phase; ph7 pre-reads next ph0.
#define ITER8H(kb) do { \
    /* ph0 */ STG_A(6, (kb) + 96);  BAR(); WAITL0();           PRIO1(); LDAH(1, 0);              MMLO(0, 0); PRIO0(); \
    /* ph1 */ STG_B(7, (kb) + 96);  BAR(); WAITL0();           PRIO1(); LDAL(0, 2); LDB_(1, 3);  MMHI(1, 0); PRIO0(); \
    /* ph2 */ STG_A(0, (kb) + 128); BAR(); WAITL0(); WAITV(6); PRIO1(); LDAH(1, 2);              MMLO(0, 1); PRIO0(); \
    /* ph3 */ STG_B(1, (kb) + 128); BAR(); WAITL0();           PRIO1(); LDAL(0, 4); LDB_(0, 5);  MMHI(1, 1); PRIO0(); \
    /* ph4 */ STG_A(2, (kb) + 160); BAR(); WAITL0(); WAITV(4); PRIO1(); LDAH(1, 4);              MMLO(0, 0); PRIO0(); \
    /* ph5 */ STG_B(3, (kb) + 160); BAR(); WAITL0();           PRIO1(); LDAL(0, 6); LDB_(1, 7);  MMHI(1, 0); PRIO0(); \
    /* ph6 */ STG_A(4, (kb) + 192); BAR(); WAITL0(); WAITV(6); PRIO1(); LDAH(1, 6);              MMLO(0, 1); PRIO0(); \
    /* ph7 */ STG_B(5, (kb) + 192); BAR(); WAITL0(); WAITV(4); PRIO1(); LDAL(0, 0); LDB_(0, 1);  MMHI(1, 1); PRIO0(); \
} while (0)

// Last iteration: only kb+96 half-tile staged; waits adjusted; no ph7 pre-read.
#define ITER8H_LAST(kb) do { \
    STG_A(6, (kb) + 96); BAR(); WAITL0();           PRIO1(); LDAH(1, 0);              MMLO(0, 0); PRIO0(); \
    STG_B(7, (kb) + 96); BAR(); WAITL0();           PRIO1(); LDAL(0, 2); LDB_(1, 3);  MMHI(1, 0); PRIO0(); \
                         BAR(); WAITL0(); WAITV(4); PRIO1(); LDAH(1, 2);              MMLO(0, 1); PRIO0(); \
                         BAR(); WAITL0();           PRIO1(); LDAL(0, 4); LDB_(0, 5);  MMHI(1, 1); PRIO0(); \
                         BAR(); WAITL0(); WAITV(0); PRIO1(); LDAH(1, 4);              MMLO(0, 0); PRIO0(); \
                         BAR(); WAITL0();           PRIO1(); LDAL(0, 6); LDB_(1, 7);  MMHI(1, 0); PRIO0(); \
                         BAR(); WAITL0();           PRIO1(); LDAH(1, 6);              MMLO(0, 1); PRIO0(); \
                         BAR(); WAITL0();           PRIO1();                          MMHI(1, 1); PRIO0(); \
} while (0)

// ---------------- merged gate+up GEMM (gathered A rows), silu epilogue ----------------
__global__ __launch_bounds__(512, 1) void k_gateup(
    const unsigned short* __restrict__ xb,
    const unsigned short* __restrict__ wgut,
    const int* __restrict__ rowlist,
    const int* __restrict__ meta,
    unsigned short* __restrict__ h,
    int cbase)
{
    extern __shared__ unsigned short smem[];
    int2 sb = strip_swz32();
    const int bx = sb.x, by = sb.y;
    const int p0 = cbase + by * 256;
    if (p0 >= meta[12]) return;
    const int e = (p0 >= meta[9]) + (p0 >= meta[10]) + (p0 >= meta[11]);

    const int tid = threadIdx.x;
    const int wid = tid >> 6, lane = tid & 63;
    const int wm = wid >> 2, wn = wid & 3;
    const int lrow = lane & 15, lkq = lane >> 4;

    // coalesced staging: inst j of wave wid covers rows 32*wid+16*j..+15;
    // lane l -> row +(l>>2), chunk (l&3)^((l>>3)&3) (quad = one 64B line).
    const int lsub = lane >> 2;                        // 0..15
    const int kc = ((lane & 3) ^ ((lane >> 3) & 3)) * 8;
    const int row0 = 32 * wid + lsub;
    const int dc0 = wid * 1024, dc1 = dc0 + 512;       // linear dest

    const unsigned short* aptr0 = xb + (size_t)rowlist[p0 + row0] * C_DIM + kc;
    const unsigned short* aptr1 = xb + (size_t)rowlist[p0 + row0 + 16] * C_DIM + kc;
    const unsigned short* Bb = wgut + (size_t)e * (2 * C_DIM * FF_DIM) + (size_t)(bx * 256) * C_DIM;
    const unsigned short* bptr0 = Bb + (size_t)row0 * C_DIM + kc;
    const unsigned short* bptr1 = Bb + (size_t)(row0 + 16) * C_DIM + kc;

    // read side: granule (row>>4)*512 elems; q = 4*lrow + (lkq ^ ((lrow>>1)&3))
    const int q8 = (4 * lrow + (lkq ^ ((lrow >> 1) & 3))) * 8;
    const int rdA = wm * 4096 + q8;    // granule base wm*8 * 512
    const int rdB = wn * 2048 + q8;    // granule base wn*4 * 512

    f32x4 acc[8][4] = {};
    bf16x8 af[2][4], bv[2][4];

    STG_A(0, 0);
    STG_B(1, 0);
    STG_A(2, 32);
    STG_B(3, 32);
    STG_A(4, 64);
    STG_B(5, 64);
    WAITV(4);          // confirms slots 0..3; {4,5} in flight
    BAR();
    LDAL(0, 0);        // prologue pre-read for ph0
    LDB_(0, 1);

    const int NI = C_DIM / 128;            // 8
    #pragma unroll 1
    for (int i = 0; i < NI - 1; ++i) {
        const int kb = 128 * i;
        ITER8H(kb);
    }
    ITER8H_LAST(128 * (NI - 1));

    // epilogue: h = silu(gate) * up
    const int ffb = bx * 128 + wn * 32;
    #pragma unroll
    for (int mi = 0; mi < 8; ++mi) {
        int row = by * 256 + wm * 128 + mi * 16 + lkq * 4;   // chunk-relative h row
        #pragma unroll
        for (int j = 0; j < 2; ++j) {
            int ff = ffb + 16 * j + lrow;
            f32x4 g = acc[mi][2 * j];
            f32x4 u = acc[mi][2 * j + 1];
            #pragma unroll
            for (int r = 0; r < 4; ++r) {
                float gv = g[r];
                float hv = gv / (1.f + __expf(-gv)) * u[r];
                h[(size_t)(row + r) * FF_DIM + ff] = f2bf(hv);
            }
        }
    }
}

// ---------------- down GEMM, single-barrier core, split-tail aware ----------------
// sp=1 (grid y=80): by<64 -> full-K (ni=32) bf16 yd tile (256 blocks = exactly
// one dispatch round, always fully occupied since meta[12]>=16384). by in
// [64,80) encodes the 16 tail tiles x 4-way K-split: u=by-64, tile by=64+(u&3),
// K-slice z=u>>2 (ni=8, kbase=z*1024), cwg-scaled f32 partials to plane z of
// part (xb space, dead after gateup; 4 planes x 4 MB). Fixes the 272-tile
// 2-round packing tail (~110 us idle CU time) -> makespan ~ 124+31 us.
// sp=0: legacy uniform path (chunked fallback).
__global__ __launch_bounds__(512, 1) void k_down(
    const unsigned short* __restrict__ h,
    const unsigned short* __restrict__ wdt,
    const float* __restrict__ cwg,
    const int* __restrict__ meta,
    unsigned short* __restrict__ yd,
    float* __restrict__ part,
    int cbase, int sp)
{
    extern __shared__ unsigned short smem[];
    int2 sb = xcd_swz(gridDim.x, gridDim.y);
    const int bx = sb.x;
    int byv = sb.y;
    int z = 0, ni = FF_DIM / 128;          // 32
    if (sp && byv >= 64) {
        int u = byv - 64;
        z = u >> 2;
        byv = 64 + (u & 3);
        ni = 8;                            // quarter K
    }
    const int p0 = cbase + byv * 256;
    if (p0 >= meta[12]) return;
    const int e = (p0 >= meta[9]) + (p0 >= meta[10]) + (p0 >= meta[11]);
    const int kbase = z * 1024;

    const int tid = threadIdx.x;
    const int wid = tid >> 6, lane = tid & 63;
    const int wm = wid >> 2, wn = wid & 3;
    const int lrow = lane & 15, lkq = lane >> 4;

    const int lsub = lane >> 2;
    const int kc = ((lane & 3) ^ ((lane >> 3) & 3)) * 8;
    const int row0 = 32 * wid + lsub;
    const int dc0 = wid * 1024, dc1 = dc0 + 512;

    const unsigned short* Ab = h + (size_t)(byv * 256) * FF_DIM;   // chunk-relative packed rows
    const unsigned short* aptr0 = Ab + (size_t)row0 * FF_DIM + kc + kbase;
    const unsigned short* aptr1 = Ab + (size_t)(row0 + 16) * FF_DIM + kc + kbase;
    const unsigned short* Bb = wdt + (size_t)e * (C_DIM * FF_DIM) + (size_t)(bx * 256) * FF_DIM;
    const unsigned short* bptr0 = Bb + (size_t)row0 * FF_DIM + kc + kbase;
    const unsigned short* bptr1 = Bb + (size_t)(row0 + 16) * FF_DIM + kc + kbase;

    const int q8 = (4 * lrow + (lkq ^ ((lrow >> 1) & 3))) * 8;
    const int rdA = wm * 4096 + q8;
    const int rdB = wn * 2048 + q8;

    f32x4 acc[8][4] = {};
    bf16x8 af[2][4], bv[2][4];

    STG_A(0, 0);
    STG_B(1, 0);
    STG_A(2, 32);
    STG_B(3, 32);
    STG_A(4, 64);
    STG_B(5, 64);
    WAITV(4);
    BAR();
    LDAL(0, 0);
    LDB_(0, 1);

    #pragma unroll 1
    for (int i = 0; i < ni - 1; ++i) {
        const int kb = 128 * i;
        ITER8H(kb);
    }
    ITER8H_LAST(128 * (ni - 1));

    // epilogue (pads have cwg=0; rows unread)
    if (ni == 32) {
        #pragma unroll
        for (int mi = 0; mi < 8; ++mi) {
            int pb = p0 + wm * 128 + mi * 16 + lkq * 4;
            float w4[4];
            #pragma unroll
            for (int r = 0; r < 4; ++r) w4[r] = cwg[pb + r];
            #pragma unroll
            for (int ni_ = 0; ni_ < 4; ++ni_) {
                int col = bx * 256 + wn * 64 + ni_ * 16 + lrow;
                f32x4 a = acc[mi][ni_];
                #pragma unroll
                for (int r = 0; r < 4; ++r)
                    yd[(size_t)(pb + r) * C_DIM + col] = f2bf(w4[r] * a[r]);
            }
        }
    } else {
        float* pl = part + (size_t)z * PART_PLANE;
        #pragma unroll
        for (int mi = 0; mi < 8; ++mi) {
            int pb = p0 + wm * 128 + mi * 16 + lkq * 4;
            float w4[4];
            #pragma unroll
            for (int r = 0; r < 4; ++r) w4[r] = cwg[pb + r];
            #pragma unroll
            for (int ni_ = 0; ni_ < 4; ++ni_) {
                int col = bx * 256 + wn * 64 + ni_ * 16 + lrow;
                f32x4 a = acc[mi][ni_];
                #pragma unroll
                for (int r = 0; r < 4; ++r)
                    pl[(size_t)(pb + r - SPLIT_P0) * C_DIM + col] = w4[r] * a[r];
            }
        }
    }
}

// ---------------- combine: out[t] = slot(pA) + slot(pB) (deterministic) ----------------
// sp=1: slots >= SPLIT_P0 come from the 4 f32 K-partial planes (summed f32 --
// one bf16 rounding fewer than the yd path). sp=0: all slots from bf16 yd.
__global__ void k_combine(const unsigned short* __restrict__ yd, const float* __restrict__ part,
                          const int* __restrict__ pos2, float* __restrict__ out, int sp) {
    int t = blockIdx.x;
    int c4 = threadIdx.x * 4;
    float4 s[2];
    #pragma unroll
    for (int j = 0; j < 2; ++j) {
        int p = pos2[t * 2 + j];
        if (!sp || p < SPLIT_P0) {
            ushort4 a = *(const ushort4*)(yd + (size_t)p * C_DIM + c4);
            s[j] = make_float4(bf2f(a.x), bf2f(a.y), bf2f(a.z), bf2f(a.w));
        } else {
            size_t base = (size_t)(p - SPLIT_P0) * C_DIM + c4;
            float4 acc = make_float4(0.f, 0.f, 0.f, 0.f);
            #pragma unroll
            for (int z = 0; z < 4; ++z) {
                float4 v = *(const float4*)(part + (size_t)z * PART_PLANE + base);
                acc.x += v.x; acc.y += v.y; acc.z += v.z; acc.w += v.w;
            }
            s[j] = acc;
        }
    }
    float4 o;
    o.x = s[0].x + s[1].x;
    o.y = s[0].y + s[1].y;
    o.z = s[0].z + s[1].z;
    o.w = s[0].w + s[1].w;
    *(float4*)(out + (size_t)t * C_DIM + c4) = o;
}

extern "C" void kernel_launch(void* const* d_in, const int* in_sizes, int n_in,
                              void* d_out, int out_size, void* d_ws, size_t ws_size,
                              hipStream_t stream) {
    (void)in_sizes; (void)n_in; (void)out_size;
    const float* x   = (const float*)d_in[0];
    const float* w_r = (const float*)d_in[1];
    const float* w_g = (const float*)d_in[2];
    const float* w_u = (const float*)d_in[3];
    const float* w_d = (const float*)d_in[4];
    float* out = (float*)d_out;

    char* ws = (char*)d_ws;
    unsigned short* xb   = (unsigned short*)(ws);                    // 16,777,216
    unsigned short* wgut = (unsigned short*)(ws + 16777216);         // 67,108,864
    unsigned short* wdt  = (unsigned short*)(ws + 83886080);         // 33,554,432
    unsigned short* yd   = (unsigned short*)(ws + 117440512);        // 35,651,584 (17408 x 1024)
    float*          cw   = (float*)(ws + 153092096);                 //    131,072
    int*            rowlist = (int*)(ws + 153223168);                //     69,632
    float*          cwg  = (float*)(ws + 153292800);                 //     69,632
    int*            pos2 = (int*)(ws + 153362432);                   //     65,536
    int*            meta = (int*)(ws + 153427968);                   //        512
    unsigned short* h    = (unsigned short*)(ws + 153428480);        // chunked: 2 MiB / 256-row block
    float*          part = (float*)(ws);                             // tail K-partials: reuses xb space
                                                                     // (dead after gateup; 4 x 4 MB, exact fit)

    hipFuncSetAttribute((const void*)k_gateup, hipFuncAttributeMaxDynamicSharedMemorySize, 8 * SLOT_E * 2);
    hipFuncSetAttribute((const void*)k_down,   hipFuncAttributeMaxDynamicSharedMemorySize, 8 * SLOT_E * 2);

    size_t h_avail = ws_size > 153428480 ? ws_size - 153428480 : 0;
    int maxb = (int)(h_avail / (256 * FF_DIM * 2));   // 2 MiB per 256-row block
    if (maxb < 1) maxb = 1;
    if (maxb > TOTB256) maxb = TOTB256;
    int nch = (TOTB256 + maxb - 1) / maxb;

    k_router<<<N_TOK / 4, 256, 0, stream>>>(x, w_r, cw, xb);
    k_build<<<1, 256, 0, stream>>>(cw, rowlist, cwg, pos2, meta);

    k_tconv<<<dim3(FF_DIM / 64, C_DIM / 64, NE), 256, 0, stream>>>(w_g, wgut, C_DIM, FF_DIM, (size_t)2 * C_DIM * FF_DIM, 1, 0);
    k_tconv<<<dim3(FF_DIM / 64, C_DIM / 64, NE), 256, 0, stream>>>(w_u, wgut, C_DIM, FF_DIM, (size_t)2 * C_DIM * FF_DIM, 1, 16);
    k_tconv<<<dim3(C_DIM / 64, FF_DIM / 64, NE), 256, 0, stream>>>(w_d, wdt, FF_DIM, C_DIM, (size_t)C_DIM * FF_DIM, 0, 0);

    if (nch == 1) {
        // single-chunk path: xb is dead after the one gateup launch -> part can
        // reuse it; down uses split-tail grid (4 x 80) for ~1.25-round packing.
        k_gateup<<<dim3(2 * FF_DIM / 256, TOTB256), 512, 8 * SLOT_E * 2, stream>>>(xb, wgut, rowlist, meta, h, 0);
        k_down<<<dim3(C_DIM / 256, 80), 512, 8 * SLOT_E * 2, stream>>>(h, wdt, cwg, meta, yd, part, 0, 1);
        k_combine<<<N_TOK, 256, 0, stream>>>(yd, part, pos2, out, 1);
    } else {
        for (int c = 0; c < nch; ++c) {
            int cb = c * maxb;
            int nb = (TOTB256 - cb) < maxb ? (TOTB256 - cb) : maxb;
            k_gateup<<<dim3(2 * FF_DIM / 256, nb), 512, 8 * SLOT_E * 2, stream>>>(xb, wgut, rowlist, meta, h, cb * 256);
            k_down<<<dim3(C_DIM / 256, nb), 512, 8 * SLOT_E * 2, stream>>>(h, wdt, cwg, meta, yd, part, cb * 256, 0);
        }
        k_combine<<<N_TOK, 256, 0, stream>>>(yd, part, pos2, out, 0);
    }
}

// Round 13
// 585.671 us; speedup vs baseline: 1.0892x; 1.0624x over previous
//
#include <hip/hip_runtime.h>
#include <hip/hip_bf16.h>

#define N_TOK 8192
#define C_DIM 1024
#define FF_DIM 4096
#define NE 4
#define ROWS_MAX 17408           // max padded packed rows (16384 + 4*256 slack)
#define TOTB256 68               // ROWS_MAX / 256
#define LASTB 15                 // last-chunk rows (K-split path); planes fit wgut: 4*15*256*1024*4 = 62.9MB <= 64MB
#define PLANE_LAST 3932160       // 15*256*1024 f32 elems per K-partial plane

typedef __attribute__((ext_vector_type(8))) short bf16x8;
typedef __attribute__((ext_vector_type(4))) float f32x4;

__device__ __forceinline__ unsigned short f2bf(float f) {
    union { float f; unsigned int u; } v; v.f = f;
    return (unsigned short)((v.u + 0x7FFFu + ((v.u >> 16) & 1u)) >> 16);
}
__device__ __forceinline__ float bf2f(unsigned short u) {
    union { unsigned int u; float f; } v; v.u = ((unsigned int)u) << 16;
    return v.f;
}

__device__ __forceinline__ void gload_lds16(const void* g, void* l) {
    __builtin_amdgcn_global_load_lds(
        (const __attribute__((address_space(1))) unsigned int*)g,
        (__attribute__((address_space(3))) unsigned int*)l, 16, 0, 0);
}

#define WAITV(N) do { asm volatile("s_waitcnt vmcnt(" #N ")" ::: "memory"); __builtin_amdgcn_sched_barrier(0); } while (0)
#define WAITL0()  do { asm volatile("s_waitcnt lgkmcnt(0)" ::: "memory"); __builtin_amdgcn_sched_barrier(0); } while (0)
#define BAR()     do { __builtin_amdgcn_s_barrier(); __builtin_amdgcn_sched_barrier(0); } while (0)
#define PRIO1()   __builtin_amdgcn_s_setprio(1)
#define PRIO0()   __builtin_amdgcn_s_setprio(0)

// bijective XCD-aware block swizzle (m204): contiguous id-chunks per XCD (k_down)
__device__ __forceinline__ int2 xcd_swz(int gx, int gy) {
    int wg = blockIdx.y * gx + blockIdx.x;
    int nwg = gx * gy;
    int q = nwg >> 3, r = nwg & 7;
    int xcd = wg & 7, idx = wg >> 3;
    int swz = (xcd < r) ? (xcd * (q + 1) + idx) : (r * (q + 1) + (xcd - r) * q + idx);
    return make_int2(swz % gx, swz / gx);
}

// gateup strip swizzle (gx==32 only): each XCD owns a 4-bx column strip; its 32
// concurrent blocks form 4bx x 8by -> B working set L2-resident.
__device__ __forceinline__ int2 strip_swz32() {
    int wg = blockIdx.y * 32 + blockIdx.x;
    int xcd = wg & 7, idx = wg >> 3;
    int bx = xcd * 4 + (idx & 3);
    int by = (idx >> 4) * 4 + ((idx >> 2) & 3);
    return make_int2(bx, by);
}

// ------- transpose+convert: src fp32 [z][R][S] -> dst bf16 [z][S][R]
__global__ void k_tconv(const float* __restrict__ src0, unsigned short* __restrict__ dst0,
                        int R, int S, size_t dz, int perm, int guoff) {
    __shared__ float tile[64][65];
    const float* src = src0 + (size_t)blockIdx.z * R * S;
    unsigned short* dst = dst0 + (size_t)blockIdx.z * dz;
    const int tc = blockIdx.x * 64;
    const int tr = blockIdx.y * 64;
    const int tid = threadIdx.x;
    const int lr = tid >> 4;          // 0..15
    const int lc4 = (tid & 15) * 4;   // 0..60
    #pragma unroll
    for (int i = 0; i < 64; i += 16) {
        float4 v = *(const float4*)(src + (size_t)(tr + lr + i) * S + tc + lc4);
        tile[lr + i][lc4 + 0] = v.x;
        tile[lr + i][lc4 + 1] = v.y;
        tile[lr + i][lc4 + 2] = v.z;
        tile[lr + i][lc4 + 3] = v.w;
    }
    __syncthreads();
    const int oc = tid >> 4;          // 0..15
    const int r4 = (tid & 15) * 4;    // 0..60
    #pragma unroll
    for (int i = 0; i < 64; i += 16) {
        int cp = tc + oc + i;
        int rowo = perm ? (32 * (cp >> 4) + (cp & 15) + guoff) : cp;
        ushort4 o;
        o.x = f2bf(tile[r4 + 0][oc + i]);
        o.y = f2bf(tile[r4 + 1][oc + i]);
        o.z = f2bf(tile[r4 + 2][oc + i]);
        o.w = f2bf(tile[r4 + 3][oc + i]);
        *(ushort4*)(dst + (size_t)rowo * R + tr + r4) = o;
    }
}

// ---------------- router: fp32 logits, softmax, top-2 -> cw[N][4]; also emits xb ----------------
__global__ void k_router(const float* __restrict__ x, const float* __restrict__ wr,
                         float* __restrict__ cw, unsigned short* __restrict__ xb) {
    int wv = threadIdx.x >> 6, lane = threadIdx.x & 63;
    int n = blockIdx.x * 4 + wv;
    const float* xr = x + (size_t)n * C_DIM;
    unsigned short* xbr = xb + (size_t)n * C_DIM;
    const float4* wr4 = (const float4*)wr;
    float p0 = 0.f, p1 = 0.f, p2 = 0.f, p3 = 0.f;
    for (int j = 0; j < C_DIM / 64; ++j) {
        int c = j * 64 + lane;
        float xv = xr[c];
        xbr[c] = f2bf(xv);
        float4 w = wr4[c];
        p0 += xv * w.x; p1 += xv * w.y; p2 += xv * w.z; p3 += xv * w.w;
    }
    #pragma unroll
    for (int off = 32; off > 0; off >>= 1) {
        p0 += __shfl_down(p0, off);
        p1 += __shfl_down(p1, off);
        p2 += __shfl_down(p2, off);
        p3 += __shfl_down(p3, off);
    }
    if (lane == 0) {
        float l[NE] = {p0, p1, p2, p3};
        float mx = fmaxf(fmaxf(l[0], l[1]), fmaxf(l[2], l[3]));
        float e0[NE]; float s = 0.f;
        #pragma unroll
        for (int i = 0; i < NE; ++i) { e0[i] = expf(l[i] - mx); s += e0[i]; }
        #pragma unroll
        for (int i = 0; i < NE; ++i) e0[i] /= s;
        int i1 = 0;
        #pragma unroll
        for (int i = 1; i < NE; ++i) if (e0[i] > e0[i1]) i1 = i;
        int i2 = -1;
        #pragma unroll
        for (int i = 0; i < NE; ++i) { if (i == i1) continue; if (i2 < 0 || e0[i] > e0[i2]) i2 = i; }
        float o[NE] = {0.f, 0.f, 0.f, 0.f};
        o[i1] = e0[i1]; o[i2] = e0[i2];
        *(float4*)(cw + (size_t)n * 4) = make_float4(o[0], o[1], o[2], o[3]);
    }
}

// ---------------- build per-expert token lists (deterministic, token-id order) ----------------
__global__ void k_build(const float* __restrict__ cw, int* __restrict__ rowlist,
                        float* __restrict__ cwg, int* __restrict__ pos2, int* __restrict__ meta) {
    __shared__ int lcnt[256][NE];
    int tid = threadIdx.x;
    int t0 = tid * 32;
    int c[NE] = {0, 0, 0, 0};
    for (int i = 0; i < 32; ++i) {
        const float* w = cw + (size_t)(t0 + i) * NE;
        #pragma unroll
        for (int e = 0; e < NE; ++e) if (w[e] > 0.f) c[e]++;
    }
    #pragma unroll
    for (int e = 0; e < NE; ++e) lcnt[tid][e] = c[e];
    __syncthreads();
    if (tid == 0) {
        int tot[NE] = {0, 0, 0, 0};
        for (int i = 0; i < 256; ++i)
            #pragma unroll
            for (int e = 0; e < NE; ++e) { int v = lcnt[i][e]; lcnt[i][e] = tot[e]; tot[e] += v; }
        int off = 0;
        #pragma unroll
        for (int e = 0; e < NE; ++e) {
            meta[e] = tot[e];
            int p = (tot[e] + 255) & ~255;
            meta[4 + e] = p;
            meta[8 + e] = off;
            off += p;
        }
        meta[12] = off;
    }
    __syncthreads();
    int pos[NE];
    #pragma unroll
    for (int e = 0; e < NE; ++e) pos[e] = lcnt[tid][e];
    for (int i = 0; i < 32; ++i) {
        int t = t0 + i;
        const float* w = cw + (size_t)t * NE;
        int sl = 0;
        #pragma unroll
        for (int e = 0; e < NE; ++e) if (w[e] > 0.f) {
            int p = meta[8 + e] + pos[e]++;
            rowlist[p] = t;
            cwg[p] = w[e];
            pos2[t * 2 + sl] = p;
            sl++;
        }
    }
    __syncthreads();
    if (tid < NE) {
        int e = tid;
        for (int p = meta[e]; p < meta[4 + e]; ++p) {
            rowlist[meta[8 + e] + p] = 0;
            cwg[meta[8 + e] + p] = 0.f;
        }
    }
}

// ================= 8-phase full-hoist 256x256 core — single barrier per phase (R11) =================
#define SLOT_E 8192   // elems per unit slot

#define STAGE_U(P0, P1, slot, kofs) do { \
    gload_lds16((P0) + (kofs), smem + (slot) * SLOT_E + dc0); \
    gload_lds16((P1) + (kofs), smem + (slot) * SLOT_E + dc1); } while (0)
#define STG_A(slot, kofs) STAGE_U(aptr0, aptr1, slot, kofs)
#define STG_B(slot, kofs) STAGE_U(bptr0, bptr1, slot, kofs)

#define LDAL(bk, s) do { _Pragma("unroll") \
    for (int m_ = 0; m_ < 4; ++m_) af[bk][m_] = *(const bf16x8*)&smem[(s) * SLOT_E + rdA + m_ * 512]; } while (0)
#define LDAH(bk, s) do { _Pragma("unroll") \
    for (int m_ = 0; m_ < 4; ++m_) af[bk][m_] = *(const bf16x8*)&smem[(s) * SLOT_E + rdA + (4 + m_) * 512]; } while (0)
#define LDB_(bk, s) do { _Pragma("unroll") \
    for (int n_ = 0; n_ < 4; ++n_) bv[bk][n_] = *(const bf16x8*)&smem[(s) * SLOT_E + rdB + n_ * 512]; } while (0)

#define MMLO(ab, bb) do { _Pragma("unroll") \
    for (int m_ = 0; m_ < 4; ++m_) \
        _Pragma("unroll") \
        for (int n_ = 0; n_ < 4; ++n_) \
            acc[m_][n_] = __builtin_amdgcn_mfma_f32_16x16x32_bf16(af[ab][m_], bv[bb][n_], acc[m_][n_], 0, 0, 0); } while (0)
#define MMHI(ab, bb) do { _Pragma("unroll") \
    for (int m_ = 0; m_ < 4; ++m_) \
        _Pragma("unroll") \
        for (int n_ = 0; n_ < 4; ++n_) \
            acc[4 + m_][n_] = __builtin_amdgcn_mfma_f32_16x16x32_bf16(af[ab][m_], bv[bb][n_], acc[4 + m_][n_], 0, 0, 0); } while (0)

// Steady-state iteration: one barrier per phase; ph7 pre-reads next ph0.
#define ITER8H(kb) do { \
    /* ph0 */ STG_A(6, (kb) + 96);  BAR(); WAITL0();           PRIO1(); LDAH(1, 0);              MMLO(0, 0); PRIO0(); \
    /* ph1 */ STG_B(7, (kb) + 96);  BAR(); WAITL0();           PRIO1(); LDAL(0, 2); LDB_(1, 3);  MMHI(1, 0); PRIO0(); \
    /* ph2 */ STG_A(0, (kb) + 128); BAR(); WAITL0(); WAITV(6); PRIO1(); LDAH(1, 2);              MMLO(0, 1); PRIO0(); \
    /* ph3 */ STG_B(1, (kb) + 128); BAR(); WAITL0();           PRIO1(); LDAL(0, 4); LDB_(0, 5);  MMHI(1, 1); PRIO0(); \
    /* ph4 */ STG_A(2, (kb) + 160); BAR(); WAITL0(); WAITV(4); PRIO1(); LDAH(1, 4);              MMLO(0, 0); PRIO0(); \
    /* ph5 */ STG_B(3, (kb) + 160); BAR(); WAITL0();           PRIO1(); LDAL(0, 6); LDB_(1, 7);  MMHI(1, 0); PRIO0(); \
    /* ph6 */ STG_A(4, (kb) + 192); BAR(); WAITL0(); WAITV(6); PRIO1(); LDAH(1, 6);              MMLO(0, 1); PRIO0(); \
    /* ph7 */ STG_B(5, (kb) + 192); BAR(); WAITL0(); WAITV(4); PRIO1(); LDAL(0, 0); LDB_(0, 1);  MMHI(1, 1); PRIO0(); \
} while (0)

// Last iteration: only kb+96 half-tile staged; waits adjusted; no ph7 pre-read.
#define ITER8H_LAST(kb) do { \
    STG_A(6, (kb) + 96); BAR(); WAITL0();           PRIO1(); LDAH(1, 0);              MMLO(0, 0); PRIO0(); \
    STG_B(7, (kb) + 96); BAR(); WAITL0();           PRIO1(); LDAL(0, 2); LDB_(1, 3);  MMHI(1, 0); PRIO0(); \
                         BAR(); WAITL0(); WAITV(4); PRIO1(); LDAH(1, 2);              MMLO(0, 1); PRIO0(); \
                         BAR(); WAITL0();           PRIO1(); LDAL(0, 4); LDB_(0, 5);  MMHI(1, 1); PRIO0(); \
                         BAR(); WAITL0(); WAITV(0); PRIO1(); LDAH(1, 4);              MMLO(0, 0); PRIO0(); \
                         BAR(); WAITL0();           PRIO1(); LDAL(0, 6); LDB_(1, 7);  MMHI(1, 0); PRIO0(); \
                         BAR(); WAITL0();           PRIO1(); LDAH(1, 6);              MMLO(0, 1); PRIO0(); \
                         BAR(); WAITL0();           PRIO1();                          MMHI(1, 1); PRIO0(); \
} while (0)

// ---------------- merged gate+up GEMM (gathered A rows), silu epilogue ----------------
__global__ __launch_bounds__(512, 1) void k_gateup(
    const unsigned short* __restrict__ xb,
    const unsigned short* __restrict__ wgut,
    const int* __restrict__ rowlist,
    const int* __restrict__ meta,
    unsigned short* __restrict__ h,
    int cbase)
{
    extern __shared__ unsigned short smem[];
    int2 sb = strip_swz32();
    const int bx = sb.x, by = sb.y;
    const int p0 = cbase + by * 256;
    if (p0 >= meta[12]) return;
    const int e = (p0 >= meta[9]) + (p0 >= meta[10]) + (p0 >= meta[11]);

    const int tid = threadIdx.x;
    const int wid = tid >> 6, lane = tid & 63;
    const int wm = wid >> 2, wn = wid & 3;
    const int lrow = lane & 15, lkq = lane >> 4;

    // coalesced staging: inst j of wave wid covers rows 32*wid+16*j..+15;
    // lane l -> row +(l>>2), chunk (l&3)^((l>>3)&3) (quad = one 64B line).
    const int lsub = lane >> 2;                        // 0..15
    const int kc = ((lane & 3) ^ ((lane >> 3) & 3)) * 8;
    const int row0 = 32 * wid + lsub;
    const int dc0 = wid * 1024, dc1 = dc0 + 512;       // linear dest

    const unsigned short* aptr0 = xb + (size_t)rowlist[p0 + row0] * C_DIM + kc;
    const unsigned short* aptr1 = xb + (size_t)rowlist[p0 + row0 + 16] * C_DIM + kc;
    const unsigned short* Bb = wgut + (size_t)e * (2 * C_DIM * FF_DIM) + (size_t)(bx * 256) * C_DIM;
    const unsigned short* bptr0 = Bb + (size_t)row0 * C_DIM + kc;
    const unsigned short* bptr1 = Bb + (size_t)(row0 + 16) * C_DIM + kc;

    // read side: granule (row>>4)*512 elems; q = 4*lrow + (lkq ^ ((lrow>>1)&3))
    const int q8 = (4 * lrow + (lkq ^ ((lrow >> 1) & 3))) * 8;
    const int rdA = wm * 4096 + q8;    // granule base wm*8 * 512
    const int rdB = wn * 2048 + q8;    // granule base wn*4 * 512

    f32x4 acc[8][4] = {};
    bf16x8 af[2][4], bv[2][4];

    STG_A(0, 0);
    STG_B(1, 0);
    STG_A(2, 32);
    STG_B(3, 32);
    STG_A(4, 64);
    STG_B(5, 64);
    WAITV(4);          // confirms slots 0..3; {4,5} in flight
    BAR();
    LDAL(0, 0);        // prologue pre-read for ph0
    LDB_(0, 1);

    const int NI = C_DIM / 128;            // 8
    #pragma unroll 1
    for (int i = 0; i < NI - 1; ++i) {
        const int kb = 128 * i;
        ITER8H(kb);
    }
    ITER8H_LAST(128 * (NI - 1));

    // epilogue: h = silu(gate) * up
    const int ffb = bx * 128 + wn * 32;
    #pragma unroll
    for (int mi = 0; mi < 8; ++mi) {
        int row = by * 256 + wm * 128 + mi * 16 + lkq * 4;   // chunk-relative h row
        #pragma unroll
        for (int j = 0; j < 2; ++j) {
            int ff = ffb + 16 * j + lrow;
            f32x4 g = acc[mi][2 * j];
            f32x4 u = acc[mi][2 * j + 1];
            #pragma unroll
            for (int r = 0; r < 4; ++r) {
                float gv = g[r];
                float hv = gv / (1.f + __expf(-gv)) * u[r];
                h[(size_t)(row + r) * FF_DIM + ff] = f2bf(hv);
            }
        }
    }
}

// ---------------- down GEMM, single-barrier core ----------------
// sp=0: full-K (ni=32), bf16 epilogue to yd.
// sp=1 (LAST chunk only, grid z=4): 4-way K-split, ni=8, kbase=z*1024; writes
// cwg-scaled f32 partials to plane z of part (the wgut region -- dead after the
// last gateup; 4 planes x 15 rows = 62.9MB <= 64MB). Turns the last down launch
// (56 blocks x ~132us, 200 CUs idle) into 240 blocks x ~33us = one full round.
__global__ __launch_bounds__(512, 1) void k_down(
    const unsigned short* __restrict__ h,
    const unsigned short* __restrict__ wdt,
    const float* __restrict__ cwg,
    const int* __restrict__ meta,
    unsigned short* __restrict__ yd,
    float* __restrict__ part,
    int cbase, int sp)
{
    extern __shared__ unsigned short smem[];
    int2 sb = xcd_swz(gridDim.x, gridDim.y);
    const int bx = sb.x, byv = sb.y;
    const int p0 = cbase + byv * 256;
    if (p0 >= meta[12]) return;
    const int e = (p0 >= meta[9]) + (p0 >= meta[10]) + (p0 >= meta[11]);
    const int z = sp ? blockIdx.z : 0;
    const int ni = sp ? 8 : 32;
    const int kbase = z * 1024;

    const int tid = threadIdx.x;
    const int wid = tid >> 6, lane = tid & 63;
    const int wm = wid >> 2, wn = wid & 3;
    const int lrow = lane & 15, lkq = lane >> 4;

    const int lsub = lane >> 2;
    const int kc = ((lane & 3) ^ ((lane >> 3) & 3)) * 8;
    const int row0 = 32 * wid + lsub;
    const int dc0 = wid * 1024, dc1 = dc0 + 512;

    const unsigned short* Ab = h + (size_t)(byv * 256) * FF_DIM;   // chunk-relative packed rows
    const unsigned short* aptr0 = Ab + (size_t)row0 * FF_DIM + kc + kbase;
    const unsigned short* aptr1 = Ab + (size_t)(row0 + 16) * FF_DIM + kc + kbase;
    const unsigned short* Bb = wdt + (size_t)e * (C_DIM * FF_DIM) + (size_t)(bx * 256) * FF_DIM;
    const unsigned short* bptr0 = Bb + (size_t)row0 * FF_DIM + kc + kbase;
    const unsigned short* bptr1 = Bb + (size_t)(row0 + 16) * FF_DIM + kc + kbase;

    const int q8 = (4 * lrow + (lkq ^ ((lrow >> 1) & 3))) * 8;
    const int rdA = wm * 4096 + q8;
    const int rdB = wn * 2048 + q8;

    f32x4 acc[8][4] = {};
    bf16x8 af[2][4], bv[2][4];

    STG_A(0, 0);
    STG_B(1, 0);
    STG_A(2, 32);
    STG_B(3, 32);
    STG_A(4, 64);
    STG_B(5, 64);
    WAITV(4);
    BAR();
    LDAL(0, 0);
    LDB_(0, 1);

    #pragma unroll 1
    for (int i = 0; i < ni - 1; ++i) {
        const int kb = 128 * i;
        ITER8H(kb);
    }
    ITER8H_LAST(128 * (ni - 1));

    // epilogue (pads have cwg=0; rows unread)
    if (!sp) {
        #pragma unroll
        for (int mi = 0; mi < 8; ++mi) {
            int pb = p0 + wm * 128 + mi * 16 + lkq * 4;
            float w4[4];
            #pragma unroll
            for (int r = 0; r < 4; ++r) w4[r] = cwg[pb + r];
            #pragma unroll
            for (int ni_ = 0; ni_ < 4; ++ni_) {
                int col = bx * 256 + wn * 64 + ni_ * 16 + lrow;
                f32x4 a = acc[mi][ni_];
                #pragma unroll
                for (int r = 0; r < 4; ++r)
                    yd[(size_t)(pb + r) * C_DIM + col] = f2bf(w4[r] * a[r]);
            }
        }
    } else {
        float* pl = part + (size_t)z * PLANE_LAST;
        #pragma unroll
        for (int mi = 0; mi < 8; ++mi) {
            int pb = p0 + wm * 128 + mi * 16 + lkq * 4;
            float w4[4];
            #pragma unroll
            for (int r = 0; r < 4; ++r) w4[r] = cwg[pb + r];
            #pragma unroll
            for (int ni_ = 0; ni_ < 4; ++ni_) {
                int col = bx * 256 + wn * 64 + ni_ * 16 + lrow;
                f32x4 a = acc[mi][ni_];
                #pragma unroll
                for (int r = 0; r < 4; ++r)
                    pl[(size_t)(pb + r - cbase) * C_DIM + col] = w4[r] * a[r];
            }
        }
    }
}

// ---------------- combine: out[t] = slot(pA) + slot(pB) (deterministic) ----------------
// sbase >= 0: slots >= sbase come from the 4 f32 K-partial planes (f32 sums --
// one bf16 rounding fewer). sbase < 0: all slots from bf16 yd.
__global__ void k_combine(const unsigned short* __restrict__ yd, const float* __restrict__ part,
                          const int* __restrict__ pos2, float* __restrict__ out, int sbase) {
    int t = blockIdx.x;
    int c4 = threadIdx.x * 4;
    float4 s[2];
    #pragma unroll
    for (int j = 0; j < 2; ++j) {
        int p = pos2[t * 2 + j];
        if (sbase < 0 || p < sbase) {
            ushort4 a = *(const ushort4*)(yd + (size_t)p * C_DIM + c4);
            s[j] = make_float4(bf2f(a.x), bf2f(a.y), bf2f(a.z), bf2f(a.w));
        } else {
            size_t base = (size_t)(p - sbase) * C_DIM + c4;
            float4 acc = make_float4(0.f, 0.f, 0.f, 0.f);
            #pragma unroll
            for (int z = 0; z < 4; ++z) {
                float4 v = *(const float4*)(part + (size_t)z * PLANE_LAST + base);
                acc.x += v.x; acc.y += v.y; acc.z += v.z; acc.w += v.w;
            }
            s[j] = acc;
        }
    }
    float4 o;
    o.x = s[0].x + s[1].x;
    o.y = s[0].y + s[1].y;
    o.z = s[0].z + s[1].z;
    o.w = s[0].w + s[1].w;
    *(float4*)(out + (size_t)t * C_DIM + c4) = o;
}

extern "C" void kernel_launch(void* const* d_in, const int* in_sizes, int n_in,
                              void* d_out, int out_size, void* d_ws, size_t ws_size,
                              hipStream_t stream) {
    (void)in_sizes; (void)n_in; (void)out_size;
    const float* x   = (const float*)d_in[0];
    const float* w_r = (const float*)d_in[1];
    const float* w_g = (const float*)d_in[2];
    const float* w_u = (const float*)d_in[3];
    const float* w_d = (const float*)d_in[4];
    float* out = (float*)d_out;

    char* ws = (char*)d_ws;
    unsigned short* xb   = (unsigned short*)(ws);                    // 16,777,216
    unsigned short* wgut = (unsigned short*)(ws + 16777216);         // 67,108,864
    unsigned short* wdt  = (unsigned short*)(ws + 83886080);         // 33,554,432
    unsigned short* yd   = (unsigned short*)(ws + 117440512);        // 35,651,584 (17408 x 1024)
    float*          cw   = (float*)(ws + 153092096);                 //    131,072
    int*            rowlist = (int*)(ws + 153223168);                //     69,632
    float*          cwg  = (float*)(ws + 153292800);                 //     69,632
    int*            pos2 = (int*)(ws + 153362432);                   //     65,536
    int*            meta = (int*)(ws + 153427968);                   //        512
    unsigned short* h    = (unsigned short*)(ws + 153428480);        // chunked: 2 MiB / 256-row block
    float*          part = (float*)wgut;                             // last-chunk K-partials (wgut dead
                                                                     // after last gateup; 4 x 15.7MB)

    hipFuncSetAttribute((const void*)k_gateup, hipFuncAttributeMaxDynamicSharedMemorySize, 8 * SLOT_E * 2);
    hipFuncSetAttribute((const void*)k_down,   hipFuncAttributeMaxDynamicSharedMemorySize, 8 * SLOT_E * 2);

    size_t h_avail = ws_size > 153428480 ? ws_size - 153428480 : 0;
    int maxb = (int)(h_avail / (256 * FF_DIM * 2));   // 2 MiB per 256-row block
    if (maxb < 1) maxb = 1;

    k_router<<<N_TOK / 4, 256, 0, stream>>>(x, w_r, cw, xb);
    k_build<<<1, 256, 0, stream>>>(cw, rowlist, cwg, pos2, meta);

    k_tconv<<<dim3(FF_DIM / 64, C_DIM / 64, NE), 256, 0, stream>>>(w_g, wgut, C_DIM, FF_DIM, (size_t)2 * C_DIM * FF_DIM, 1, 0);
    k_tconv<<<dim3(FF_DIM / 64, C_DIM / 64, NE), 256, 0, stream>>>(w_u, wgut, C_DIM, FF_DIM, (size_t)2 * C_DIM * FF_DIM, 1, 16);
    k_tconv<<<dim3(C_DIM / 64, FF_DIM / 64, NE), 256, 0, stream>>>(w_d, wdt, FF_DIM, C_DIM, (size_t)C_DIM * FF_DIM, 0, 0);

    // Deliberate chunk plan: keep the LAST chunk at LASTB(=15) rows so its down
    // launch can 4-way K-split into the freed wgut region (one ~33us round
    // instead of a 132us 56-block round). Earlier chunks sized <= maxb.
    int plan[4]; int np = 0;
    if (maxb >= TOTB256 - LASTB) {            // 53: {53,15}
        plan[0] = TOTB256 - LASTB; plan[1] = LASTB; np = 2;
    } else if (maxb >= 27) {                  // {26,27,15}
        plan[0] = 26; plan[1] = 27; plan[2] = LASTB; np = 3;
    }

    if (np > 0) {
        int cb = 0;
        for (int c = 0; c < np; ++c) {
            int nb = plan[c];
            k_gateup<<<dim3(2 * FF_DIM / 256, nb), 512, 8 * SLOT_E * 2, stream>>>(xb, wgut, rowlist, meta, h, cb * 256);
            if (c < np - 1)
                k_down<<<dim3(C_DIM / 256, nb), 512, 8 * SLOT_E * 2, stream>>>(h, wdt, cwg, meta, yd, part, cb * 256, 0);
            else
                k_down<<<dim3(C_DIM / 256, nb, 4), 512, 8 * SLOT_E * 2, stream>>>(h, wdt, cwg, meta, yd, part, cb * 256, 1);
            cb += nb;
        }
        k_combine<<<N_TOK, 256, 0, stream>>>(yd, part, pos2, out, (TOTB256 - LASTB) * 256);
    } else {
        // generic fallback (small workspace): uniform chunks, no split
        if (maxb > TOTB256) maxb = TOTB256;
        int nch = (TOTB256 + maxb - 1) / maxb;
        for (int c = 0; c < nch; ++c) {
            int cb = c * maxb;
            int nb = (TOTB256 - cb) < maxb ? (TOTB256 - cb) : maxb;
            k_gateup<<<dim3(2 * FF_DIM / 256, nb), 512, 8 * SLOT_E * 2, stream>>>(xb, wgut, rowlist, meta, h, cb * 256);
            k_down<<<dim3(C_DIM / 256, nb), 512, 8 * SLOT_E * 2, stream>>>(h, wdt, cwg, meta, yd, part, cb * 256, 0);
        }
        k_combine<<<N_TOK, 256, 0, stream>>>(yd, part, pos2, out, -1);
    }
}

// Round 14
// 577.664 us; speedup vs baseline: 1.1042x; 1.0139x over previous
//
#include <hip/hip_runtime.h>
#include <hip/hip_bf16.h>

#define N_TOK 8192
#define C_DIM 1024
#define FF_DIM 4096
#define NE 4
#define ROWS_MAX 17408           // max padded packed rows (16384 + 4*256 slack)
#define TOTB256 68               // ROWS_MAX / 256

typedef __attribute__((ext_vector_type(8))) short bf16x8;
typedef __attribute__((ext_vector_type(4))) float f32x4;

__device__ __forceinline__ unsigned short f2bf(float f) {
    union { float f; unsigned int u; } v; v.f = f;
    return (unsigned short)((v.u + 0x7FFFu + ((v.u >> 16) & 1u)) >> 16);
}
__device__ __forceinline__ float bf2f(unsigned short u) {
    union { unsigned int u; float f; } v; v.u = ((unsigned int)u) << 16;
    return v.f;
}

__device__ __forceinline__ void gload_lds16(const void* g, void* l) {
    __builtin_amdgcn_global_load_lds(
        (const __attribute__((address_space(1))) unsigned int*)g,
        (__attribute__((address_space(3))) unsigned int*)l, 16, 0, 0);
}

#define WAITV(N) do { asm volatile("s_waitcnt vmcnt(" #N ")" ::: "memory"); __builtin_amdgcn_sched_barrier(0); } while (0)
#define WAITL0()  do { asm volatile("s_waitcnt lgkmcnt(0)" ::: "memory"); __builtin_amdgcn_sched_barrier(0); } while (0)
#define BAR()     do { __builtin_amdgcn_s_barrier(); __builtin_amdgcn_sched_barrier(0); } while (0)
#define PRIO1()   __builtin_amdgcn_s_setprio(1)
#define PRIO0()   __builtin_amdgcn_s_setprio(0)

// bijective XCD-aware block swizzle (m204): contiguous id-chunks per XCD (k_down)
__device__ __forceinline__ int2 xcd_swz(int gx, int gy) {
    int wg = blockIdx.y * gx + blockIdx.x;
    int nwg = gx * gy;
    int q = nwg >> 3, r = nwg & 7;
    int xcd = wg & 7, idx = wg >> 3;
    int swz = (xcd < r) ? (xcd * (q + 1) + idx) : (r * (q + 1) + (xcd - r) * q + idx);
    return make_int2(swz % gx, swz / gx);
}

// gateup strip swizzle (gx==32 only): each XCD owns a 4-bx column strip; its 32
// concurrent blocks form 4bx x 8by -> B working set L2-resident.
__device__ __forceinline__ int2 strip_swz32() {
    int wg = blockIdx.y * 32 + blockIdx.x;
    int xcd = wg & 7, idx = wg >> 3;
    int bx = xcd * 4 + (idx & 3);
    int by = (idx >> 4) * 4 + ((idx >> 2) & 3);
    return make_int2(bx, by);
}

// ------- transpose+convert (merged gate+up): z = e*2 + which; src fp32 [C][FF]
// -> dst bf16 interleaved [2C][FF->rows] with perm rowo = 32*(c>>4)+(c&15)+16*which
__global__ void k_tconv_gu(const float* __restrict__ g0, const float* __restrict__ u0,
                           unsigned short* __restrict__ dst0) {
    __shared__ float tile[64][65];
    const int zz = blockIdx.z;
    const int e = zz >> 1, which = zz & 1;
    const float* src = (which ? u0 : g0) + (size_t)e * C_DIM * FF_DIM;
    unsigned short* dst = dst0 + (size_t)e * (2 * C_DIM * FF_DIM);
    const int guoff = 16 * which;
    const int tc = blockIdx.x * 64;
    const int tr = blockIdx.y * 64;
    const int tid = threadIdx.x;
    const int lr = tid >> 4;          // 0..15
    const int lc4 = (tid & 15) * 4;   // 0..60
    #pragma unroll
    for (int i = 0; i < 64; i += 16) {
        float4 v = *(const float4*)(src + (size_t)(tr + lr + i) * FF_DIM + tc + lc4);
        tile[lr + i][lc4 + 0] = v.x;
        tile[lr + i][lc4 + 1] = v.y;
        tile[lr + i][lc4 + 2] = v.z;
        tile[lr + i][lc4 + 3] = v.w;
    }
    __syncthreads();
    const int oc = tid >> 4;          // 0..15
    const int r4 = (tid & 15) * 4;    // 0..60
    #pragma unroll
    for (int i = 0; i < 64; i += 16) {
        int cp = tc + oc + i;
        int rowo = 32 * (cp >> 4) + (cp & 15) + guoff;
        ushort4 o;
        o.x = f2bf(tile[r4 + 0][oc + i]);
        o.y = f2bf(tile[r4 + 1][oc + i]);
        o.z = f2bf(tile[r4 + 2][oc + i]);
        o.w = f2bf(tile[r4 + 3][oc + i]);
        *(ushort4*)(dst + (size_t)rowo * C_DIM + tr + r4) = o;
    }
}

// ------- transpose+convert (down weights): src fp32 [z][FF][C] -> dst bf16 [z][C][FF]
__global__ void k_tconv(const float* __restrict__ src0, unsigned short* __restrict__ dst0,
                        int R, int S, size_t dz) {
    __shared__ float tile[64][65];
    const float* src = src0 + (size_t)blockIdx.z * R * S;
    unsigned short* dst = dst0 + (size_t)blockIdx.z * dz;
    const int tc = blockIdx.x * 64;
    const int tr = blockIdx.y * 64;
    const int tid = threadIdx.x;
    const int lr = tid >> 4;          // 0..15
    const int lc4 = (tid & 15) * 4;   // 0..60
    #pragma unroll
    for (int i = 0; i < 64; i += 16) {
        float4 v = *(const float4*)(src + (size_t)(tr + lr + i) * S + tc + lc4);
        tile[lr + i][lc4 + 0] = v.x;
        tile[lr + i][lc4 + 1] = v.y;
        tile[lr + i][lc4 + 2] = v.z;
        tile[lr + i][lc4 + 3] = v.w;
    }
    __syncthreads();
    const int oc = tid >> 4;          // 0..15
    const int r4 = (tid & 15) * 4;    // 0..60
    #pragma unroll
    for (int i = 0; i < 64; i += 16) {
        int cp = tc + oc + i;
        ushort4 o;
        o.x = f2bf(tile[r4 + 0][oc + i]);
        o.y = f2bf(tile[r4 + 1][oc + i]);
        o.z = f2bf(tile[r4 + 2][oc + i]);
        o.w = f2bf(tile[r4 + 3][oc + i]);
        *(ushort4*)(dst + (size_t)cp * R + tr + r4) = o;
    }
}

// ---------------- router: fp32 logits, softmax, top-2 -> cw[N][4]; also emits xb ----------------
__global__ void k_router(const float* __restrict__ x, const float* __restrict__ wr,
                         float* __restrict__ cw, unsigned short* __restrict__ xb) {
    int wv = threadIdx.x >> 6, lane = threadIdx.x & 63;
    int n = blockIdx.x * 4 + wv;
    const float* xr = x + (size_t)n * C_DIM;
    unsigned short* xbr = xb + (size_t)n * C_DIM;
    const float4* wr4 = (const float4*)wr;
    float p0 = 0.f, p1 = 0.f, p2 = 0.f, p3 = 0.f;
    for (int j = 0; j < C_DIM / 64; ++j) {
        int c = j * 64 + lane;
        float xv = xr[c];
        xbr[c] = f2bf(xv);
        float4 w = wr4[c];
        p0 += xv * w.x; p1 += xv * w.y; p2 += xv * w.z; p3 += xv * w.w;
    }
    #pragma unroll
    for (int off = 32; off > 0; off >>= 1) {
        p0 += __shfl_down(p0, off);
        p1 += __shfl_down(p1, off);
        p2 += __shfl_down(p2, off);
        p3 += __shfl_down(p3, off);
    }
    if (lane == 0) {
        float l[NE] = {p0, p1, p2, p3};
        float mx = fmaxf(fmaxf(l[0], l[1]), fmaxf(l[2], l[3]));
        float e0[NE]; float s = 0.f;
        #pragma unroll
        for (int i = 0; i < NE; ++i) { e0[i] = expf(l[i] - mx); s += e0[i]; }
        #pragma unroll
        for (int i = 0; i < NE; ++i) e0[i] /= s;
        int i1 = 0;
        #pragma unroll
        for (int i = 1; i < NE; ++i) if (e0[i] > e0[i1]) i1 = i;
        int i2 = -1;
        #pragma unroll
        for (int i = 0; i < NE; ++i) { if (i == i1) continue; if (i2 < 0 || e0[i] > e0[i2]) i2 = i; }
        float o[NE] = {0.f, 0.f, 0.f, 0.f};
        o[i1] = e0[i1]; o[i2] = e0[i2];
        *(float4*)(cw + (size_t)n * 4) = make_float4(o[0], o[1], o[2], o[3]);
    }
}

// ---------------- build per-expert token lists (deterministic, token-id order) ----------------
__global__ void k_build(const float* __restrict__ cw, int* __restrict__ rowlist,
                        float* __restrict__ cwg, int* __restrict__ pos2, int* __restrict__ meta) {
    __shared__ int lcnt[256][NE];
    int tid = threadIdx.x;
    int t0 = tid * 32;
    int c[NE] = {0, 0, 0, 0};
    for (int i = 0; i < 32; ++i) {
        const float* w = cw + (size_t)(t0 + i) * NE;
        #pragma unroll
        for (int e = 0; e < NE; ++e) if (w[e] > 0.f) c[e]++;
    }
    #pragma unroll
    for (int e = 0; e < NE; ++e) lcnt[tid][e] = c[e];
    __syncthreads();
    if (tid == 0) {
        int tot[NE] = {0, 0, 0, 0};
        for (int i = 0; i < 256; ++i)
            #pragma unroll
            for (int e = 0; e < NE; ++e) { int v = lcnt[i][e]; lcnt[i][e] = tot[e]; tot[e] += v; }
        int off = 0;
        #pragma unroll
        for (int e = 0; e < NE; ++e) {
            meta[e] = tot[e];
            int p = (tot[e] + 255) & ~255;
            meta[4 + e] = p;
            meta[8 + e] = off;
            off += p;
        }
        meta[12] = off;
    }
    __syncthreads();
    int pos[NE];
    #pragma unroll
    for (int e = 0; e < NE; ++e) pos[e] = lcnt[tid][e];
    for (int i = 0; i < 32; ++i) {
        int t = t0 + i;
        const float* w = cw + (size_t)t * NE;
        int sl = 0;
        #pragma unroll
        for (int e = 0; e < NE; ++e) if (w[e] > 0.f) {
            int p = meta[8 + e] + pos[e]++;
            rowlist[p] = t;
            cwg[p] = w[e];
            pos2[t * 2 + sl] = p;
            sl++;
        }
    }
    __syncthreads();
    if (tid < NE) {
        int e = tid;
        for (int p = meta[e]; p < meta[4 + e]; ++p) {
            rowlist[meta[8 + e] + p] = 0;
            cwg[meta[8 + e] + p] = 0.f;
        }
    }
}

// ================= 8-phase full-hoist 256x256 core — single barrier per phase (R11) =================
#define SLOT_E 8192   // elems per unit slot

#define STAGE_U(P0, P1, slot, kofs) do { \
    gload_lds16((P0) + (kofs), smem + (slot) * SLOT_E + dc0); \
    gload_lds16((P1) + (kofs), smem + (slot) * SLOT_E + dc1); } while (0)
#define STG_A(slot, kofs) STAGE_U(aptr0, aptr1, slot, kofs)
#define STG_B(slot, kofs) STAGE_U(bptr0, bptr1, slot, kofs)

#define LDAL(bk, s) do { _Pragma("unroll") \
    for (int m_ = 0; m_ < 4; ++m_) af[bk][m_] = *(const bf16x8*)&smem[(s) * SLOT_E + rdA + m_ * 512]; } while (0)
#define LDAH(bk, s) do { _Pragma("unroll") \
    for (int m_ = 0; m_ < 4; ++m_) af[bk][m_] = *(const bf16x8*)&smem[(s) * SLOT_E + rdA + (4 + m_) * 512]; } while (0)
#define LDB_(bk, s) do { _Pragma("unroll") \
    for (int n_ = 0; n_ < 4; ++n_) bv[bk][n_] = *(const bf16x8*)&smem[(s) * SLOT_E + rdB + n_ * 512]; } while (0)

#define MMLO(ab, bb) do { _Pragma("unroll") \
    for (int m_ = 0; m_ < 4; ++m_) \
        _Pragma("unroll") \
        for (int n_ = 0; n_ < 4; ++n_) \
            acc[m_][n_] = __builtin_amdgcn_mfma_f32_16x16x32_bf16(af[ab][m_], bv[bb][n_], acc[m_][n_], 0, 0, 0); } while (0)
#define MMHI(ab, bb) do { _Pragma("unroll") \
    for (int m_ = 0; m_ < 4; ++m_) \
        _Pragma("unroll") \
        for (int n_ = 0; n_ < 4; ++n_) \
            acc[4 + m_][n_] = __builtin_amdgcn_mfma_f32_16x16x32_bf16(af[ab][m_], bv[bb][n_], acc[4 + m_][n_], 0, 0, 0); } while (0)

// Steady-state iteration: one barrier per phase; ph7 pre-reads next ph0.
#define ITER8H(kb) do { \
    /* ph0 */ STG_A(6, (kb) + 96);  BAR(); WAITL0();           PRIO1(); LDAH(1, 0);              MMLO(0, 0); PRIO0(); \
    /* ph1 */ STG_B(7, (kb) + 96);  BAR(); WAITL0();           PRIO1(); LDAL(0, 2); LDB_(1, 3);  MMHI(1, 0); PRIO0(); \
    /* ph2 */ STG_A(0, (kb) + 128); BAR(); WAITL0(); WAITV(6); PRIO1(); LDAH(1, 2);              MMLO(0, 1); PRIO0(); \
    /* ph3 */ STG_B(1, (kb) + 128); BAR(); WAITL0();           PRIO1(); LDAL(0, 4); LDB_(0, 5);  MMHI(1, 1); PRIO0(); \
    /* ph4 */ STG_A(2, (kb) + 160); BAR(); WAITL0(); WAITV(4); PRIO1(); LDAH(1, 4);              MMLO(0, 0); PRIO0(); \
    /* ph5 */ STG_B(3, (kb) + 160); BAR(); WAITL0();           PRIO1(); LDAL(0, 6); LDB_(1, 7);  MMHI(1, 0); PRIO0(); \
    /* ph6 */ STG_A(4, (kb) + 192); BAR(); WAITL0(); WAITV(6); PRIO1(); LDAH(1, 6);              MMLO(0, 1); PRIO0(); \
    /* ph7 */ STG_B(5, (kb) + 192); BAR(); WAITL0(); WAITV(4); PRIO1(); LDAL(0, 0); LDB_(0, 1);  MMHI(1, 1); PRIO0(); \
} while (0)

// Last iteration: only kb+96 half-tile staged; waits adjusted; no ph7 pre-read.
#define ITER8H_LAST(kb) do { \
    STG_A(6, (kb) + 96); BAR(); WAITL0();           PRIO1(); LDAH(1, 0);              MMLO(0, 0); PRIO0(); \
    STG_B(7, (kb) + 96); BAR(); WAITL0();           PRIO1(); LDAL(0, 2); LDB_(1, 3);  MMHI(1, 0); PRIO0(); \
                         BAR(); WAITL0(); WAITV(4); PRIO1(); LDAH(1, 2);              MMLO(0, 1); PRIO0(); \
                         BAR(); WAITL0();           PRIO1(); LDAL(0, 4); LDB_(0, 5);  MMHI(1, 1); PRIO0(); \
                         BAR(); WAITL0(); WAITV(0); PRIO1(); LDAH(1, 4);              MMLO(0, 0); PRIO0(); \
                         BAR(); WAITL0();           PRIO1(); LDAL(0, 6); LDB_(1, 7);  MMHI(1, 0); PRIO0(); \
                         BAR(); WAITL0();           PRIO1(); LDAH(1, 6);              MMLO(0, 1); PRIO0(); \
                         BAR(); WAITL0();           PRIO1();                          MMHI(1, 1); PRIO0(); \
} while (0)

// ---------------- merged gate+up GEMM (gathered A rows), silu epilogue ----------------
__global__ __launch_bounds__(512, 1) void k_gateup(
    const unsigned short* __restrict__ xb,
    const unsigned short* __restrict__ wgut,
    const int* __restrict__ rowlist,
    const int* __restrict__ meta,
    unsigned short* __restrict__ h,
    int cbase)
{
    extern __shared__ unsigned short smem[];
    int2 sb = strip_swz32();
    const int bx = sb.x, by = sb.y;
    const int p0 = cbase + by * 256;
    if (p0 >= meta[12]) return;
    const int e = (p0 >= meta[9]) + (p0 >= meta[10]) + (p0 >= meta[11]);

    const int tid = threadIdx.x;
    const int wid = tid >> 6, lane = tid & 63;
    const int wm = wid >> 2, wn = wid & 3;
    const int lrow = lane & 15, lkq = lane >> 4;

    // coalesced staging: inst j of wave wid covers rows 32*wid+16*j..+15;
    // lane l -> row +(l>>2), chunk (l&3)^((l>>3)&3) (quad = one 64B line).
    const int lsub = lane >> 2;                        // 0..15
    const int kc = ((lane & 3) ^ ((lane >> 3) & 3)) * 8;
    const int row0 = 32 * wid + lsub;
    const int dc0 = wid * 1024, dc1 = dc0 + 512;       // linear dest

    const unsigned short* aptr0 = xb + (size_t)rowlist[p0 + row0] * C_DIM + kc;
    const unsigned short* aptr1 = xb + (size_t)rowlist[p0 + row0 + 16] * C_DIM + kc;
    const unsigned short* Bb = wgut + (size_t)e * (2 * C_DIM * FF_DIM) + (size_t)(bx * 256) * C_DIM;
    const unsigned short* bptr0 = Bb + (size_t)row0 * C_DIM + kc;
    const unsigned short* bptr1 = Bb + (size_t)(row0 + 16) * C_DIM + kc;

    // read side: granule (row>>4)*512 elems; q = 4*lrow + (lkq ^ ((lrow>>1)&3))
    const int q8 = (4 * lrow + (lkq ^ ((lrow >> 1) & 3))) * 8;
    const int rdA = wm * 4096 + q8;    // granule base wm*8 * 512
    const int rdB = wn * 2048 + q8;    // granule base wn*4 * 512

    f32x4 acc[8][4] = {};
    bf16x8 af[2][4], bv[2][4];

    STG_A(0, 0);
    STG_B(1, 0);
    STG_A(2, 32);
    STG_B(3, 32);
    STG_A(4, 64);
    STG_B(5, 64);
    WAITV(4);          // confirms slots 0..3; {4,5} in flight
    BAR();
    LDAL(0, 0);        // prologue pre-read for ph0
    LDB_(0, 1);

    const int NI = C_DIM / 128;            // 8
    #pragma unroll 1
    for (int i = 0; i < NI - 1; ++i) {
        const int kb = 128 * i;
        ITER8H(kb);
    }
    ITER8H_LAST(128 * (NI - 1));

    // epilogue: h = silu(gate) * up
    const int ffb = bx * 128 + wn * 32;
    #pragma unroll
    for (int mi = 0; mi < 8; ++mi) {
        int row = by * 256 + wm * 128 + mi * 16 + lkq * 4;   // chunk-relative h row
        #pragma unroll
        for (int j = 0; j < 2; ++j) {
            int ff = ffb + 16 * j + lrow;
            f32x4 g = acc[mi][2 * j];
            f32x4 u = acc[mi][2 * j + 1];
            #pragma unroll
            for (int r = 0; r < 4; ++r) {
                float gv = g[r];
                float hv = gv / (1.f + __expf(-gv)) * u[r];
                h[(size_t)(row + r) * FF_DIM + ff] = f2bf(hv);
            }
        }
    }
}

// ---------------- down GEMM, single-barrier core ----------------
// sp=0: full-K (ni=32), bf16 epilogue to yd.
// sp=1 (LAST chunk only, grid z=4): 4-way K-split, ni=8, kbase=z*1024; writes
// cwg-scaled f32 partials (plane stride plane_e) into part = wgut region (dead
// after the last gateup; 4*lastb*256*1024*4 B <= 64MB for lastb <= 16).
__global__ __launch_bounds__(512, 1) void k_down(
    const unsigned short* __restrict__ h,
    const unsigned short* __restrict__ wdt,
    const float* __restrict__ cwg,
    const int* __restrict__ meta,
    unsigned short* __restrict__ yd,
    float* __restrict__ part,
    int cbase, int sp, int plane_e)
{
    extern __shared__ unsigned short smem[];
    int2 sb = xcd_swz(gridDim.x, gridDim.y);
    const int bx = sb.x, byv = sb.y;
    const int p0 = cbase + byv * 256;
    if (p0 >= meta[12]) return;
    const int e = (p0 >= meta[9]) + (p0 >= meta[10]) + (p0 >= meta[11]);
    const int z = sp ? blockIdx.z : 0;
    const int ni = sp ? 8 : 32;
    const int kbase = z * 1024;

    const int tid = threadIdx.x;
    const int wid = tid >> 6, lane = tid & 63;
    const int wm = wid >> 2, wn = wid & 3;
    const int lrow = lane & 15, lkq = lane >> 4;

    const int lsub = lane >> 2;
    const int kc = ((lane & 3) ^ ((lane >> 3) & 3)) * 8;
    const int row0 = 32 * wid + lsub;
    const int dc0 = wid * 1024, dc1 = dc0 + 512;

    const unsigned short* Ab = h + (size_t)(byv * 256) * FF_DIM;   // chunk-relative packed rows
    const unsigned short* aptr0 = Ab + (size_t)row0 * FF_DIM + kc + kbase;
    const unsigned short* aptr1 = Ab + (size_t)(row0 + 16) * FF_DIM + kc + kbase;
    const unsigned short* Bb = wdt + (size_t)e * (C_DIM * FF_DIM) + (size_t)(bx * 256) * FF_DIM;
    const unsigned short* bptr0 = Bb + (size_t)row0 * FF_DIM + kc + kbase;
    const unsigned short* bptr1 = Bb + (size_t)(row0 + 16) * FF_DIM + kc + kbase;

    const int q8 = (4 * lrow + (lkq ^ ((lrow >> 1) & 3))) * 8;
    const int rdA = wm * 4096 + q8;
    const int rdB = wn * 2048 + q8;

    f32x4 acc[8][4] = {};
    bf16x8 af[2][4], bv[2][4];

    STG_A(0, 0);
    STG_B(1, 0);
    STG_A(2, 32);
    STG_B(3, 32);
    STG_A(4, 64);
    STG_B(5, 64);
    WAITV(4);
    BAR();
    LDAL(0, 0);
    LDB_(0, 1);

    #pragma unroll 1
    for (int i = 0; i < ni - 1; ++i) {
        const int kb = 128 * i;
        ITER8H(kb);
    }
    ITER8H_LAST(128 * (ni - 1));

    // epilogue (pads have cwg=0; rows unread)
    if (!sp) {
        #pragma unroll
        for (int mi = 0; mi < 8; ++mi) {
            int pb = p0 + wm * 128 + mi * 16 + lkq * 4;
            float w4[4];
            #pragma unroll
            for (int r = 0; r < 4; ++r) w4[r] = cwg[pb + r];
            #pragma unroll
            for (int ni_ = 0; ni_ < 4; ++ni_) {
                int col = bx * 256 + wn * 64 + ni_ * 16 + lrow;
                f32x4 a = acc[mi][ni_];
                #pragma unroll
                for (int r = 0; r < 4; ++r)
                    yd[(size_t)(pb + r) * C_DIM + col] = f2bf(w4[r] * a[r]);
            }
        }
    } else {
        float* pl = part + (size_t)z * plane_e;
        #pragma unroll
        for (int mi = 0; mi < 8; ++mi) {
            int pb = p0 + wm * 128 + mi * 16 + lkq * 4;
            float w4[4];
            #pragma unroll
            for (int r = 0; r < 4; ++r) w4[r] = cwg[pb + r];
            #pragma unroll
            for (int ni_ = 0; ni_ < 4; ++ni_) {
                int col = bx * 256 + wn * 64 + ni_ * 16 + lrow;
                f32x4 a = acc[mi][ni_];
                #pragma unroll
                for (int r = 0; r < 4; ++r)
                    pl[(size_t)(pb + r - cbase) * C_DIM + col] = w4[r] * a[r];
            }
        }
    }
}

// ---------------- combine: out[t] = slot(pA) + slot(pB) (deterministic) ----------------
// sbase >= 0: slots >= sbase come from the 4 f32 K-partial planes (f32 sums --
// one bf16 rounding fewer). sbase < 0: all slots from bf16 yd.
__global__ void k_combine(const unsigned short* __restrict__ yd, const float* __restrict__ part,
                          const int* __restrict__ pos2, float* __restrict__ out,
                          int sbase, int plane_e) {
    int t = blockIdx.x;
    int c4 = threadIdx.x * 4;
    float4 s[2];
    #pragma unroll
    for (int j = 0; j < 2; ++j) {
        int p = pos2[t * 2 + j];
        if (sbase < 0 || p < sbase) {
            ushort4 a = *(const ushort4*)(yd + (size_t)p * C_DIM + c4);
            s[j] = make_float4(bf2f(a.x), bf2f(a.y), bf2f(a.z), bf2f(a.w));
        } else {
            size_t base = (size_t)(p - sbase) * C_DIM + c4;
            float4 acc = make_float4(0.f, 0.f, 0.f, 0.f);
            #pragma unroll
            for (int z = 0; z < 4; ++z) {
                float4 v = *(const float4*)(part + (size_t)z * plane_e + base);
                acc.x += v.x; acc.y += v.y; acc.z += v.z; acc.w += v.w;
            }
            s[j] = acc;
        }
    }
    float4 o;
    o.x = s[0].x + s[1].x;
    o.y = s[0].y + s[1].y;
    o.z = s[0].z + s[1].z;
    o.w = s[0].w + s[1].w;
    *(float4*)(out + (size_t)t * C_DIM + c4) = o;
}

extern "C" void kernel_launch(void* const* d_in, const int* in_sizes, int n_in,
                              void* d_out, int out_size, void* d_ws, size_t ws_size,
                              hipStream_t stream) {
    (void)in_sizes; (void)n_in; (void)out_size;
    const float* x   = (const float*)d_in[0];
    const float* w_r = (const float*)d_in[1];
    const float* w_g = (const float*)d_in[2];
    const float* w_u = (const float*)d_in[3];
    const float* w_d = (const float*)d_in[4];
    float* out = (float*)d_out;

    char* ws = (char*)d_ws;
    unsigned short* xb   = (unsigned short*)(ws);                    // 16,777,216
    unsigned short* wgut = (unsigned short*)(ws + 16777216);         // 67,108,864
    unsigned short* wdt  = (unsigned short*)(ws + 83886080);         // 33,554,432
    unsigned short* yd   = (unsigned short*)(ws + 117440512);        // 35,651,584 (17408 x 1024)
    float*          cw   = (float*)(ws + 153092096);                 //    131,072
    int*            rowlist = (int*)(ws + 153223168);                //     69,632
    float*          cwg  = (float*)(ws + 153292800);                 //     69,632
    int*            pos2 = (int*)(ws + 153362432);                   //     65,536
    int*            meta = (int*)(ws + 153427968);                   //        512
    unsigned short* h    = (unsigned short*)(ws + 153428480);        // chunked: 2 MiB / 256-row block
    float*          part = (float*)wgut;                             // last-chunk K-partials (wgut dead
                                                                     // after last gateup; <= 64MB)

    hipFuncSetAttribute((const void*)k_gateup, hipFuncAttributeMaxDynamicSharedMemorySize, 8 * SLOT_E * 2);
    hipFuncSetAttribute((const void*)k_down,   hipFuncAttributeMaxDynamicSharedMemorySize, 8 * SLOT_E * 2);

    size_t h_avail = ws_size > 153428480 ? ws_size - 153428480 : 0;
    int maxb = (int)(h_avail / (256 * FF_DIM * 2));   // 2 MiB per 256-row block
    if (maxb < 1) maxb = 1;

    k_router<<<N_TOK / 4, 256, 0, stream>>>(x, w_r, cw, xb);
    k_build<<<1, 256, 0, stream>>>(cw, rowlist, cwg, pos2, meta);

    k_tconv_gu<<<dim3(FF_DIM / 64, C_DIM / 64, 2 * NE), 256, 0, stream>>>(w_g, w_u, wgut);
    k_tconv<<<dim3(C_DIM / 64, FF_DIM / 64, NE), 256, 0, stream>>>(w_d, wdt, FF_DIM, C_DIM, (size_t)C_DIM * FF_DIM);

    // Deliberate chunk plan: keep the LAST chunk small (4..16 rows) so its down
    // launch can 4-way K-split into the freed wgut region (one ~33us round
    // instead of a ~132us partial round). plan0 <= 64 keeps down1 <= 256 blocks
    // (exactly one dispatch round).
    int plan[4]; int np = 0; int lastb = 0;
    if (maxb >= 52) {
        int p0n = maxb < 64 ? maxb : 64;
        lastb = TOTB256 - p0n;                 // 4..16 -> planes fit 64MB
        plan[0] = p0n; plan[1] = lastb; np = 2;
    } else if (maxb >= 27) {
        lastb = 15;
        plan[0] = 26; plan[1] = 27; plan[2] = 15; np = 3;
    }

    if (np > 0) {
        int plane_e = lastb * 256 * 1024;
        int cb = 0;
        for (int c = 0; c < np; ++c) {
            int nb = plan[c];
            k_gateup<<<dim3(2 * FF_DIM / 256, nb), 512, 8 * SLOT_E * 2, stream>>>(xb, wgut, rowlist, meta, h, cb * 256);
            if (c < np - 1)
                k_down<<<dim3(C_DIM / 256, nb), 512, 8 * SLOT_E * 2, stream>>>(h, wdt, cwg, meta, yd, part, cb * 256, 0, plane_e);
            else
                k_down<<<dim3(C_DIM / 256, nb, 4), 512, 8 * SLOT_E * 2, stream>>>(h, wdt, cwg, meta, yd, part, cb * 256, 1, plane_e);
            cb += nb;
        }
        k_combine<<<N_TOK, 256, 0, stream>>>(yd, part, pos2, out, (TOTB256 - lastb) * 256, plane_e);
    } else {
        // generic fallback (small workspace): uniform chunks, no split
        if (maxb > TOTB256) maxb = TOTB256;
        int nch = (TOTB256 + maxb - 1) / maxb;
        for (int c = 0; c < nch; ++c) {
            int cb = c * maxb;
            int nb = (TOTB256 - cb) < maxb ? (TOTB256 - cb) : maxb;
            k_gateup<<<dim3(2 * FF_DIM / 256, nb), 512, 8 * SLOT_E * 2, stream>>>(xb, wgut, rowlist, meta, h, cb * 256);
            k_down<<<dim3(C_DIM / 256, nb), 512, 8 * SLOT_E * 2, stream>>>(h, wdt, cwg, meta, yd, part, cb * 256, 0, 0);
        }
        k_combine<<<N_TOK, 256, 0, stream>>>(yd, part, pos2, out, -1, 0);
    }
}